// Round 8
// baseline (714.095 us; speedup 1.0000x reference)
//
#include <hip/hip_runtime.h>
#include <hip/hip_bf16.h>
#include <cstdio>

// ---------------------------------------------------------------------------
// MixtralTransformerDecoder: B=2 S=2048 H=1024 NQ=16 NKV=4 HD=64 I=3584 E=8
// TOP_K=2, sliding window 512.
// Split-bf16 (hi+lo) MFMA upstream of the router; plain bf16 MFMA for experts.
// R8: revert R7's vmcnt rotation on gemm_split/attn (regressed: low-TLP +
// VALU-phase kernels want the compiler's drain form). down retiled to
// BN=256 / wave 64x64 (2.0 MFMA per ds_read) with 3-stage counted vmcnt +
// XCD chunk swizzle. gateup stays at R3/R6 config (verified best).
// ---------------------------------------------------------------------------

typedef __bf16 bf16x8 __attribute__((ext_vector_type(8)));
typedef float f32x4 __attribute__((ext_vector_type(4)));

#define MFMA16(a, b, c) __builtin_amdgcn_mfma_f32_16x16x32_bf16((a), (b), (c), 0, 0, 0)
#define GL16(g, l)                                                             \
  __builtin_amdgcn_global_load_lds(                                            \
      (const __attribute__((address_space(1))) void*)(g),                      \
      (__attribute__((address_space(3))) void*)(l), 16, 0, 0)
#define WAIT_VM0() asm volatile("s_waitcnt vmcnt(0)" ::: "memory")
#define SETPRIO(n) __builtin_amdgcn_s_setprio(n)
// counted-vmcnt + raw barrier + compiler fence (T4; __syncthreads would drain)
#define PIPE_SYNC(n)                                                           \
  do {                                                                         \
    asm volatile("s_waitcnt vmcnt(" #n ")" ::: "memory");                      \
    __builtin_amdgcn_s_barrier();                                              \
    asm volatile("" ::: "memory");                                             \
  } while (0)

__device__ __forceinline__ unsigned short f2bf(float f) {
  unsigned u = __builtin_bit_cast(unsigned, f);
  u += 0x7fffu + ((u >> 16) & 1u);
  return (unsigned short)(u >> 16);
}
__device__ __forceinline__ float bf2f(unsigned short h) {
  unsigned u = ((unsigned)h) << 16;
  return __builtin_bit_cast(float, u);
}
// swizzled element offset for [row][32 bf16] LDS tiles (64B rows, 4 chunks)
__device__ __forceinline__ int sw32(int row, int chunk) {
  return row * 32 + ((chunk ^ ((row >> 1) & 3)) * 8);
}

// ---------------------------------------------------------------------------
// Workspace layout (bytes)
// ---------------------------------------------------------------------------
static constexpr size_t O_WQKVT_HI = 0;                           // [1536][1024] bf16
static constexpr size_t SZ_WQKVT   = 1536UL * 1024 * 2;
static constexpr size_t O_WQKVT_LO = O_WQKVT_HI + SZ_WQKVT;
static constexpr size_t O_WOT_HI   = O_WQKVT_LO + SZ_WQKVT;       // [1024][1024] bf16
static constexpr size_t SZ_WOT     = 1024UL * 1024 * 2;
static constexpr size_t O_WOT_LO   = O_WOT_HI + SZ_WOT;
static constexpr size_t O_WGT      = O_WOT_LO + SZ_WOT;           // [8][3584][1024] bf16
static constexpr size_t SZ_WE      = 8UL * 3584 * 1024 * 2;
static constexpr size_t O_WUT      = O_WGT + SZ_WE;
static constexpr size_t O_WDT      = O_WUT + SZ_WE;               // [8][1024][3584] bf16
static constexpr size_t O_H2       = O_WDT + SZ_WE;               // [4096][1024] bf16
static constexpr size_t SZ_BF_TH   = 4096UL * 1024 * 2;
static constexpr size_t O_TOK      = O_H2 + SZ_BF_TH;             // [8][4096] i32
static constexpr size_t O_WGTL     = O_TOK + 8UL * 4096 * 4;      // [8][4096] f32
static constexpr size_t O_CNT      = O_WGTL + 8UL * 4096 * 4;     // [8] i32
static constexpr size_t O_DYN      = O_CNT + 256;
// DYN region (dead before MoE; ACT aliases its head)
static constexpr size_t O_HSHI  = O_DYN;
static constexpr size_t O_HSLO  = O_HSHI + SZ_BF_TH;
static constexpr size_t O_QKV   = O_HSLO + SZ_BF_TH;              // [4096][1536] f32
static constexpr size_t O_QHI   = O_QKV + 4096UL * 1536 * 4;      // [2][16][2048][64] bf16
static constexpr size_t O_QLO   = O_QHI + SZ_BF_TH;
static constexpr size_t O_KHI   = O_QLO + SZ_BF_TH;               // [2][4][2048][64] bf16
static constexpr size_t SZ_BF_T256 = 4096UL * 256 * 2;
static constexpr size_t O_KLO   = O_KHI + SZ_BF_T256;
static constexpr size_t O_VTH   = O_KLO + SZ_BF_T256;             // [2][4][64][2048] bf16
static constexpr size_t O_VTL   = O_VTH + SZ_BF_T256;
static constexpr size_t O_AHI   = O_VTL + SZ_BF_T256;             // [4096][1024] bf16
static constexpr size_t O_ALO   = O_AHI + SZ_BF_TH;
static constexpr size_t O_XATTN = O_ALO + SZ_BF_TH;               // [4096][1024] f32
static constexpr size_t O_END   = O_XATTN + 4096UL * 1024 * 4;
static constexpr size_t O_ACT   = O_DYN;   // [<=9208][3584] bf16 alias (66MB, before XATTN)
static constexpr size_t WS_NEED = O_END;

// ---------------------------------------------------------------------------
// small kernels
// ---------------------------------------------------------------------------
__global__ void zero_cnt_kernel(int* c) {
  if (threadIdx.x < 8) c[threadIdx.x] = 0;
}

__global__ __launch_bounds__(256) void init_out_kernel(const float* __restrict__ x,
                                                       float* __restrict__ o) {
  const long i = (long)blockIdx.x * 256 + threadIdx.x;  // 1M float4
  *(float4*)&o[i * 4] = *(const float4*)&x[i * 4];
}

// RMSNorm: x[4096][1024] f32 -> hi (+ optional lo) bf16
__global__ __launch_bounds__(256) void rmsnorm_kernel(const float* __restrict__ x,
                                                      const float* __restrict__ scale,
                                                      unsigned short* __restrict__ hi,
                                                      unsigned short* __restrict__ lo) {
  const int t = blockIdx.x, tid = threadIdx.x;
  const float4 v = *(const float4*)&x[(long)t * 1024 + tid * 4];
  float ss = v.x * v.x + v.y * v.y + v.z * v.z + v.w * v.w;
#pragma unroll
  for (int off = 32; off >= 1; off >>= 1) ss += __shfl_down(ss, off);
  __shared__ float red[4];
  if ((tid & 63) == 0) red[tid >> 6] = ss;
  __syncthreads();
  const float r = rsqrtf((red[0] + red[1] + red[2] + red[3]) * (1.0f / 1024.0f) + 1e-5f);
  const float4 sc = *(const float4*)&scale[tid * 4];
  float o[4] = {v.x * r * sc.x, v.y * r * sc.y, v.z * r * sc.z, v.w * r * sc.w};
  ushort4 hh, ll;
  unsigned short* hp = (unsigned short*)&hh;
  unsigned short* lp = (unsigned short*)&ll;
#pragma unroll
  for (int i = 0; i < 4; ++i) {
    hp[i] = f2bf(o[i]);
    lp[i] = f2bf(o[i] - bf2f(hp[i]));
  }
  *(ushort4*)&hi[(long)t * 1024 + tid * 4] = hh;
  if (lo) *(ushort4*)&lo[(long)t * 1024 + tid * 4] = ll;
}

// transpose+convert: src f32 [R][C] -> dst bf16 [C][R]
__global__ __launch_bounds__(256) void transpose_cvt(const float* __restrict__ src,
                                                     unsigned short* __restrict__ dst,
                                                     int R, int C, long zsrc, long zdst) {
  src += (long)blockIdx.z * zsrc;
  dst += (long)blockIdx.z * zdst;
  const int c0 = blockIdx.x * 64, r0 = blockIdx.y * 64, tid = threadIdx.x;
  __shared__ float tb[64][65];
#pragma unroll
  for (int p = 0; p < 4; ++p) {
    const int r = p * 16 + (tid >> 4), c = (tid & 15) * 4;
    const float4 v = *(const float4*)&src[(long)(r0 + r) * C + c0 + c];
    tb[c + 0][r] = v.x; tb[c + 1][r] = v.y; tb[c + 2][r] = v.z; tb[c + 3][r] = v.w;
  }
  __syncthreads();
  const int dr = tid >> 2, s0 = (tid & 3) * 16;
  __align__(16) unsigned short tmp[16];
#pragma unroll
  for (int i = 0; i < 16; ++i) tmp[i] = f2bf(tb[dr][s0 + i]);
  const long o = (long)(c0 + dr) * R + r0 + s0;
  *(uint4*)&dst[o] = *(const uint4*)&tmp[0];
  *(uint4*)&dst[o + 8] = *(const uint4*)&tmp[8];
}

// transpose+convert+split: src f32 [R][C] -> hi,lo bf16 [C][R]
__global__ __launch_bounds__(256) void transpose_cvt_split(const float* __restrict__ src,
                                                           unsigned short* __restrict__ dh,
                                                           unsigned short* __restrict__ dl,
                                                           int R, int C) {
  const int c0 = blockIdx.x * 64, r0 = blockIdx.y * 64, tid = threadIdx.x;
  __shared__ float tb[64][65];
#pragma unroll
  for (int p = 0; p < 4; ++p) {
    const int r = p * 16 + (tid >> 4), c = (tid & 15) * 4;
    const float4 v = *(const float4*)&src[(long)(r0 + r) * C + c0 + c];
    tb[c + 0][r] = v.x; tb[c + 1][r] = v.y; tb[c + 2][r] = v.z; tb[c + 3][r] = v.w;
  }
  __syncthreads();
  const int dr = tid >> 2, s0 = (tid & 3) * 16;
  __align__(16) unsigned short th[16], tl[16];
#pragma unroll
  for (int i = 0; i < 16; ++i) {
    const float f = tb[dr][s0 + i];
    th[i] = f2bf(f);
    tl[i] = f2bf(f - bf2f(th[i]));
  }
  const long o = (long)(c0 + dr) * R + r0 + s0;
  *(uint4*)&dh[o] = *(const uint4*)&th[0];
  *(uint4*)&dh[o + 8] = *(const uint4*)&th[8];
  *(uint4*)&dl[o] = *(const uint4*)&tl[0];
  *(uint4*)&dl[o + 8] = *(const uint4*)&tl[8];
}

// ---------------------------------------------------------------------------
// split-bf16 GEMM: C[M][N] = (Ahi+Alo)[M][K] @ (Bhi+Blo)[N][K]^T (+resid)
// 128x128 tile, BK=32, dbuf prefetch + swizzle + setprio (R6 form).
// ---------------------------------------------------------------------------
__global__ __launch_bounds__(256) void gemm_split(const unsigned short* __restrict__ Ahi,
                                                  const unsigned short* __restrict__ Alo,
                                                  const unsigned short* __restrict__ Bhi,
                                                  const unsigned short* __restrict__ Blo,
                                                  const float* __restrict__ resid,
                                                  float* __restrict__ C,
                                                  int M, int N, int K) {
  __shared__ unsigned short Ash[2][4096], Asl[2][4096], Bsh[2][4096], Bsl[2][4096];
  const int tid = threadIdx.x, wid = tid >> 6, lane = tid & 63;
  const int m0 = blockIdx.y * 128, n0 = blockIdx.x * 128;
  const int wm = (wid >> 1) * 64, wn = (wid & 1) * 64;
  const int fr = lane & 15, fg = lane >> 4;
  const int srow = tid >> 2;
  const int scol = (((tid & 3) ^ ((tid >> 3) & 3))) * 8;  // swizzled source chunk
  const long aoff = (long)(m0 + srow) * K + scol;
  const long boff = (long)(n0 + srow) * K + scol;
  const long h64 = 64L * K;
  char* a0 = (char*)Ash[0] + wid * 1024; char* a1 = (char*)Ash[1] + wid * 1024;
  char* al0 = (char*)Asl[0] + wid * 1024; char* al1 = (char*)Asl[1] + wid * 1024;
  char* b0 = (char*)Bsh[0] + wid * 1024; char* b1 = (char*)Bsh[1] + wid * 1024;
  char* bl0 = (char*)Bsl[0] + wid * 1024; char* bl1 = (char*)Bsl[1] + wid * 1024;
#define GS_STAGE(koff, pah_, pal_, pbh_, pbl_)                                 \
  do {                                                                         \
    GL16(Ahi + aoff + (koff), (pah_));                                         \
    GL16(Ahi + aoff + h64 + (koff), (pah_) + 4096);                            \
    GL16(Alo + aoff + (koff), (pal_));                                         \
    GL16(Alo + aoff + h64 + (koff), (pal_) + 4096);                            \
    GL16(Bhi + boff + (koff), (pbh_));                                         \
    GL16(Bhi + boff + h64 + (koff), (pbh_) + 4096);                            \
    GL16(Blo + boff + (koff), (pbl_));                                         \
    GL16(Blo + boff + h64 + (koff), (pbl_) + 4096);                            \
  } while (0)
  f32x4 acc[4][4] = {};
  GS_STAGE(0, a0, al0, b0, bl0);
  WAIT_VM0();
  __syncthreads();
  int cur = 0;
  for (int k0 = 0; k0 < K; k0 += 32) {
    const int kn = k0 + 32;
    if (kn < K) {
      if (cur) GS_STAGE(kn, a0, al0, b0, bl0);
      else     GS_STAGE(kn, a1, al1, b1, bl1);
    }
    const unsigned short* As_ = Ash[cur];
    const unsigned short* Al_ = Asl[cur];
    const unsigned short* Bs_ = Bsh[cur];
    const unsigned short* Bl_ = Bsl[cur];
    bf16x8 ah[4], al[4], bh[4], bl[4];
#pragma unroll
    for (int i = 0; i < 4; ++i) {
      const int oA = sw32(wm + i * 16 + fr, fg);
      const int oB = sw32(wn + i * 16 + fr, fg);
      ah[i] = *(const bf16x8*)&As_[oA];
      al[i] = *(const bf16x8*)&Al_[oA];
      bh[i] = *(const bf16x8*)&Bs_[oB];
      bl[i] = *(const bf16x8*)&Bl_[oB];
    }
    SETPRIO(1);
#pragma unroll
    for (int i = 0; i < 4; ++i)
#pragma unroll
      for (int j = 0; j < 4; ++j) {
        acc[i][j] = MFMA16(al[i], bh[j], acc[i][j]);
        acc[i][j] = MFMA16(ah[i], bl[j], acc[i][j]);
        acc[i][j] = MFMA16(ah[i], bh[j], acc[i][j]);
      }
    SETPRIO(0);
    WAIT_VM0();
    __syncthreads();
    cur ^= 1;
  }
#undef GS_STAGE
  const int cr = fg * 4;
#pragma unroll
  for (int i = 0; i < 4; ++i)
#pragma unroll
    for (int j = 0; j < 4; ++j)
#pragma unroll
      for (int rr = 0; rr < 4; ++rr) {
        const int row = m0 + wm + i * 16 + cr + rr;
        const int col = n0 + wn + j * 16 + fr;
        float v = acc[i][j][rr];
        if (resid) v += resid[(long)row * N + col];
        C[(long)row * N + col] = v;
      }
}

// ---------------------------------------------------------------------------
// RoPE + split: qkv f32 [4096][1536] -> Qhi/Qlo (scaled 1/8), Khi/Klo
// ---------------------------------------------------------------------------
__global__ __launch_bounds__(256) void rope_kernel(const float* __restrict__ qkv,
                                                   unsigned short* __restrict__ Qh,
                                                   unsigned short* __restrict__ Ql,
                                                   unsigned short* __restrict__ Kh,
                                                   unsigned short* __restrict__ Kl) {
  const int t = blockIdx.x, b = t >> 11, s = t & 2047;
  const float* src = qkv + (long)t * 1536;
  for (int task = threadIdx.x; task < 640; task += 256) {
    const int head = task >> 5, p = task & 31;
    const float* hp = src + head * 64;
    const float inv = (float)exp2(-(double)p * 0.4152410118609203);  // 10000^(-p/32)
    const float f = (float)s * inv;
    float sn, cs;
    sincosf(f, &sn, &cs);
    const float x0 = hp[2 * p], x1 = hp[2 * p + 1], xa = hp[p], xb = hp[32 + p];
    float o0 = x0 * cs - xb * sn;
    float o1 = x1 * cs + xa * sn;
    unsigned short *dh, *dl;
    long base;
    if (head < 16) {
      o0 *= 0.125f; o1 *= 0.125f;  // fold 1/sqrt(64) into Q
      base = ((long)(b * 16 + head) * 2048 + s) * 64;
      dh = Qh; dl = Ql;
    } else {
      base = ((long)(b * 4 + (head - 16)) * 2048 + s) * 64;
      dh = Kh; dl = Kl;
    }
    unsigned short h0 = f2bf(o0);
    dh[base + 2 * p] = h0; dl[base + 2 * p] = f2bf(o0 - bf2f(h0));
    unsigned short h1 = f2bf(o1);
    dh[base + 2 * p + 1] = h1; dl[base + 2 * p + 1] = f2bf(o1 - bf2f(h1));
  }
}

// V transpose+split: -> Vth/Vtl [2][4][64][2048] bf16
__global__ __launch_bounds__(256) void vt_split_kernel(const float* __restrict__ qkv,
                                                       unsigned short* __restrict__ Vh,
                                                       unsigned short* __restrict__ Vl) {
  const int st = blockIdx.x * 64, g = blockIdx.y, b = blockIdx.z, tid = threadIdx.x;
  __shared__ float tb[64][65];
  const float* src = qkv + (long)(b * 2048 + st) * 1536 + 1280 + g * 64;
#pragma unroll
  for (int p = 0; p < 4; ++p) {
    const int r = p * 16 + (tid >> 4), c = (tid & 15) * 4;
    const float4 v = *(const float4*)&src[(long)r * 1536 + c];
    tb[c + 0][r] = v.x; tb[c + 1][r] = v.y; tb[c + 2][r] = v.z; tb[c + 3][r] = v.w;
  }
  __syncthreads();
  const int dr = tid >> 2, s0 = (tid & 3) * 16;
  __align__(16) unsigned short hh[16], ll[16];
#pragma unroll
  for (int i = 0; i < 16; ++i) {
    const float f = tb[dr][s0 + i];
    hh[i] = f2bf(f);
    ll[i] = f2bf(f - bf2f(hh[i]));
  }
  const long dst = ((long)(b * 4 + g) * 64 + dr) * 2048 + st + s0;
  *(uint4*)&Vh[dst] = *(const uint4*)&hh[0];
  *(uint4*)&Vh[dst + 8] = *(const uint4*)&hh[8];
  *(uint4*)&Vl[dst] = *(const uint4*)&ll[0];
  *(uint4*)&Vl[dst + 8] = *(const uint4*)&ll[8];
}

// ---------------------------------------------------------------------------
// Flash attention, split-bf16 MFMA, sliding window 512, causal (R6 form).
// ---------------------------------------------------------------------------
__global__ __launch_bounds__(256) void attn_kernel(const unsigned short* __restrict__ Qh,
                                                   const unsigned short* __restrict__ Ql,
                                                   const unsigned short* __restrict__ Kh,
                                                   const unsigned short* __restrict__ Kl,
                                                   const unsigned short* __restrict__ Vh,
                                                   const unsigned short* __restrict__ Vl,
                                                   unsigned short* __restrict__ Ohi,
                                                   unsigned short* __restrict__ Olo) {
  const int qt = blockIdx.x, h = blockIdx.y, b = blockIdx.z, g = h >> 2;
  const int q0 = qt * 64, tid = threadIdx.x, wid = tid >> 6, lane = tid & 63;
  const int fr = lane & 15, fg = lane >> 4;
  __shared__ unsigned short Ksh[2][2048], Ksl[2][2048];  // [32 keys][64 d]
  __shared__ unsigned short Vsh[2][2048], Vsl[2][2048];  // [64 d][32 keys]
  __shared__ unsigned short Ph[4][512], Pl[4][512];      // per-wave [16][32]

  const long qoff = ((long)(b * 16 + h) * 2048 + q0 + wid * 16 + fr) * 64;
  bf16x8 qh[2], ql[2];
  qh[0] = *(const bf16x8*)&Qh[qoff + fg * 8];
  qh[1] = *(const bf16x8*)&Qh[qoff + 32 + fg * 8];
  ql[0] = *(const bf16x8*)&Ql[qoff + fg * 8];
  ql[1] = *(const bf16x8*)&Ql[qoff + 32 + fg * 8];

  f32x4 o[4] = {};
  float mrow[4], lrow[4];
#pragma unroll
  for (int rr = 0; rr < 4; ++rr) { mrow[rr] = -1e30f; lrow[rr] = 0.f; }

  const int jmin = (q0 >= 511) ? (q0 - 511) : 0;
  const int jt0 = jmin & ~31;
  const long kbase = ((long)(b * 4 + g) * 2048) * 64;
  const long vbase = ((long)(b * 4 + g) * 64) * 2048;
  const int srK = tid >> 3;                                  // 0..31
  const int scK = (((tid & 7) ^ (srK & 7))) * 8;             // swizzled K source chunk
  const int srV = tid >> 2;                                  // 0..63
  const int scV = (((tid & 3) ^ ((srV >> 1) & 3))) * 8;      // swizzled V source chunk
  char* kh0 = (char*)Ksh[0] + wid * 1024; char* kh1 = (char*)Ksh[1] + wid * 1024;
  char* kl0 = (char*)Ksl[0] + wid * 1024; char* kl1 = (char*)Ksl[1] + wid * 1024;
  char* vh0 = (char*)Vsh[0] + wid * 1024; char* vh1 = (char*)Vsh[1] + wid * 1024;
  char* vl0 = (char*)Vsl[0] + wid * 1024; char* vl1 = (char*)Vsl[1] + wid * 1024;
#define ATTN_STAGE(jt_, kh_, kl_, vh_, vl_)                                    \
  do {                                                                         \
    const long ko = kbase + (long)((jt_) + srK) * 64 + scK;                    \
    GL16(Kh + ko, (kh_));                                                      \
    GL16(Kl + ko, (kl_));                                                      \
    const long vo = vbase + (long)srV * 2048 + (jt_) + scV;                    \
    GL16(Vh + vo, (vh_));                                                      \
    GL16(Vl + vo, (vl_));                                                      \
  } while (0)

  ATTN_STAGE(jt0, kh0, kl0, vh0, vl0);
  WAIT_VM0();
  __syncthreads();
  int cur = 0;
  for (int jt = jt0; jt < q0 + 64; jt += 32) {
    const int jn = jt + 32;
    if (jn < q0 + 64) {
      if (cur) ATTN_STAGE(jn, kh0, kl0, vh0, vl0);
      else     ATTN_STAGE(jn, kh1, kl1, vh1, vl1);
    }
    const unsigned short* KH = Ksh[cur];
    const unsigned short* KL = Ksl[cur];
    const unsigned short* VH = Vsh[cur];
    const unsigned short* VL = Vsl[cur];

    // ---- QK^T (3-term split); K rows 128B -> chunk ^= row&7 ----
    f32x4 sf[2] = {};
#pragma unroll
    for (int cf = 0; cf < 2; ++cf)
#pragma unroll
      for (int dc = 0; dc < 2; ++dc) {
        const int row = cf * 16 + fr;
        const int off = row * 64 + (((dc * 4 + fg) ^ (row & 7)) * 8);
        const bf16x8 kh = *(const bf16x8*)&KH[off];
        const bf16x8 kl = *(const bf16x8*)&KL[off];
        sf[cf] = MFMA16(ql[dc], kh, sf[cf]);
        sf[cf] = MFMA16(qh[dc], kl, sf[cf]);
        sf[cf] = MFMA16(qh[dc], kh, sf[cf]);
      }

    // ---- mask + online softmax ----
    float sv[2][4];
#pragma unroll
    for (int cf = 0; cf < 2; ++cf) {
      const int j = jt + cf * 16 + fr;
#pragma unroll
      for (int rr = 0; rr < 4; ++rr) {
        const int q = q0 + wid * 16 + fg * 4 + rr;
        const bool ok = (j <= q) && (j >= q - 511);
        sv[cf][rr] = ok ? sf[cf][rr] : -1e30f;
      }
    }
    float scl_[4];
#pragma unroll
    for (int rr = 0; rr < 4; ++rr) {
      float mx = fmaxf(sv[0][rr], sv[1][rr]);
      mx = fmaxf(mx, __shfl_xor(mx, 1));
      mx = fmaxf(mx, __shfl_xor(mx, 2));
      mx = fmaxf(mx, __shfl_xor(mx, 4));
      mx = fmaxf(mx, __shfl_xor(mx, 8));
      const float mn = fmaxf(mrow[rr], mx);
      scl_[rr] = __expf(mrow[rr] - mn);
      mrow[rr] = mn;
    }
    float ps[2][4], rs[4] = {0.f, 0.f, 0.f, 0.f};
#pragma unroll
    for (int cf = 0; cf < 2; ++cf)
#pragma unroll
      for (int rr = 0; rr < 4; ++rr) {
        const float p = (sv[cf][rr] > -1e29f) ? __expf(sv[cf][rr] - mrow[rr]) : 0.f;
        ps[cf][rr] = p;
        rs[rr] += p;
      }
#pragma unroll
    for (int rr = 0; rr < 4; ++rr) {
      float r = rs[rr];
      r += __shfl_xor(r, 1);
      r += __shfl_xor(r, 2);
      r += __shfl_xor(r, 4);
      r += __shfl_xor(r, 8);
      lrow[rr] = lrow[rr] * scl_[rr] + r;
      o[0][rr] *= scl_[rr]; o[1][rr] *= scl_[rr];
      o[2][rr] *= scl_[rr]; o[3][rr] *= scl_[rr];
    }
    // ---- P -> LDS (split, swizzled [16 q][32 k]) ----
#pragma unroll
    for (int cf = 0; cf < 2; ++cf)
#pragma unroll
      for (int rr = 0; rr < 4; ++rr) {
        const int q = fg * 4 + rr, k = cf * 16 + fr;
        const int idx = q * 32 + (((k >> 3) ^ ((q >> 1) & 3)) * 8) + (k & 7);
        const unsigned short hb = f2bf(ps[cf][rr]);
        Ph[wid][idx] = hb;
        Pl[wid][idx] = f2bf(ps[cf][rr] - bf2f(hb));
      }
    const int pro = sw32(fr, fg);
    const bf16x8 pah = *(const bf16x8*)&Ph[wid][pro];
    const bf16x8 pal = *(const bf16x8*)&Pl[wid][pro];
    // ---- PV (3-term split); V rows 64B -> sw32 ----
#pragma unroll
    for (int df = 0; df < 4; ++df) {
      const int vo = sw32(df * 16 + fr, fg);
      const bf16x8 vh = *(const bf16x8*)&VH[vo];
      const bf16x8 vl = *(const bf16x8*)&VL[vo];
      o[df] = MFMA16(pal, vh, o[df]);
      o[df] = MFMA16(pah, vl, o[df]);
      o[df] = MFMA16(pah, vh, o[df]);
    }
    WAIT_VM0();
    __syncthreads();
    cur ^= 1;
  }
#undef ATTN_STAGE
  // ---- epilogue: normalize, split, store ----
#pragma unroll
  for (int df = 0; df < 4; ++df)
#pragma unroll
    for (int rr = 0; rr < 4; ++rr) {
      const int q = q0 + wid * 16 + fg * 4 + rr;
      const float v = o[df][rr] / lrow[rr];
      const long oi = ((long)(b * 2048 + q)) * 1024 + h * 64 + df * 16 + fr;
      const unsigned short hb = f2bf(v);
      Ohi[oi] = hb;
      Olo[oi] = f2bf(v - bf2f(hb));
    }
}

// ---------------------------------------------------------------------------
// Router: inline f32 rmsnorm of XATTN, f32 logits, top-2, compaction lists.
// ---------------------------------------------------------------------------
__global__ __launch_bounds__(256) void router_kernel(const float* __restrict__ xattn,
                                                     const float* __restrict__ scale,
                                                     const float* __restrict__ wr,
                                                     float* __restrict__ logits,
                                                     int* __restrict__ tok,
                                                     float* __restrict__ wgt,
                                                     int* __restrict__ cnt) {
  const int t = blockIdx.x, tid = threadIdx.x;
  const float4 v = *(const float4*)&xattn[(long)t * 1024 + tid * 4];
  float ss = v.x * v.x + v.y * v.y + v.z * v.z + v.w * v.w;
#pragma unroll
  for (int off = 32; off >= 1; off >>= 1) ss += __shfl_down(ss, off);
  __shared__ float red[4];
  __shared__ float redE[4][8];
  __shared__ float lg[8];
  if ((tid & 63) == 0) red[tid >> 6] = ss;
  __syncthreads();
  const float r = rsqrtf((red[0] + red[1] + red[2] + red[3]) * (1.0f / 1024.0f) + 1e-5f);
  const float4 sc = *(const float4*)&scale[tid * 4];
  const float hv[4] = {v.x * r * sc.x, v.y * r * sc.y, v.z * r * sc.z, v.w * r * sc.w};
  float part[8];
#pragma unroll
  for (int e = 0; e < 8; ++e) part[e] = 0.f;
#pragma unroll
  for (int i = 0; i < 4; ++i) {
    const float* w = &wr[(long)(tid * 4 + i) * 8];
#pragma unroll
    for (int e = 0; e < 8; ++e) part[e] = fmaf(hv[i], w[e], part[e]);
  }
#pragma unroll
  for (int off = 32; off >= 1; off >>= 1)
#pragma unroll
    for (int e = 0; e < 8; ++e) part[e] += __shfl_down(part[e], off);
  if ((tid & 63) == 0)
#pragma unroll
    for (int e = 0; e < 8; ++e) redE[tid >> 6][e] = part[e];
  __syncthreads();
  if (tid < 8) {
    const float l8 = redE[0][tid] + redE[1][tid] + redE[2][tid] + redE[3][tid];
    lg[tid] = l8;
    logits[(long)t * 8 + tid] = l8;
  }
  __syncthreads();
  if (tid == 0) {
    float mx = lg[0];
#pragma unroll
    for (int e = 1; e < 8; ++e) mx = fmaxf(mx, lg[e]);
    float p[8];
#pragma unroll
    for (int e = 0; e < 8; ++e) p[e] = __expf(lg[e] - mx);
    int i1 = 0;
#pragma unroll
    for (int e = 1; e < 8; ++e) if (p[e] > p[i1]) i1 = e;
    int i2 = (i1 == 0) ? 1 : 0;
#pragma unroll
    for (int e = 0; e < 8; ++e) if (e != i2 && e != i1 && p[e] > p[i2]) i2 = e;
    const float wsum = p[i1] + p[i2];
    const float w1 = p[i1] / wsum, w2 = p[i2] / wsum;
    const int pos1 = atomicAdd(&cnt[i1], 1);
    tok[i1 * 4096 + pos1] = t; wgt[i1 * 4096 + pos1] = w1;
    const int pos2 = atomicAdd(&cnt[i2], 1);
    tok[i2 * 4096 + pos2] = t; wgt[i2 * 4096 + pos2] = w2;
  }
}

// ---------------------------------------------------------------------------
// MoE gate+up fused GEMM (gathered A): act = silu(h2@Wg^T) * (h2@Wu^T), bf16
// R3 structure: 512 threads (8 waves, 2Mx4N), 3-stage pipeline, vmcnt(3).
// + XCD chunk swizzle.
// ---------------------------------------------------------------------------
__global__ __launch_bounds__(512, 4) void gateup_kernel(const unsigned short* __restrict__ H2,
                                                        const unsigned short* __restrict__ WG,
                                                        const unsigned short* __restrict__ WU,
                                                        const int* __restrict__ tok,
                                                        const int* __restrict__ cnt,
                                                        unsigned short* __restrict__ act) {
  // XCD chunk swizzle (bijective: 7168 % 8 == 0)
  const int flat = blockIdx.x + 28 * (blockIdx.y + 32 * blockIdx.z);
  const int w = (flat & 7) * 896 + (flat >> 3);
  const int bx = w % 28, by = (w / 28) & 31, e = w / 896;
  const int cn = cnt[e];
  const int m0 = by * 128;
  if (m0 >= cn) return;
  int padoff = 0;
  for (int i = 0; i < e; ++i) padoff += (cnt[i] + 127) & ~127;
  const int n0 = bx * 128;
  __shared__ unsigned short As[3][4096], Bg[3][4096], Bu[3][4096];
  const int tid = threadIdx.x, wid = tid >> 6, lane = tid & 63;
  const int wm = (wid >> 2) * 64, wn = (wid & 3) * 32;
  const int fr = lane & 15, fg = lane >> 4;
  const int srow = tid >> 2;                               // 0..127
  const int scol = (((tid & 3) ^ ((tid >> 3) & 3))) * 8;   // swizzled source chunk
  const int lr = m0 + srow;
  const int tkr = (lr < cn) ? tok[e * 4096 + lr] : 0;
  const unsigned short* ga = H2 + (long)tkr * 1024 + scol;
  const unsigned short* gb = WG + (long)e * 3584 * 1024 + (long)(n0 + srow) * 1024 + scol;
  const unsigned short* gu = WU + (long)e * 3584 * 1024 + (long)(n0 + srow) * 1024 + scol;
#define GU_STAGE(s, b)                                                         \
  do {                                                                         \
    const int ko = (s) * 32;                                                   \
    GL16(ga + ko, (char*)As[b] + wid * 1024);                                  \
    GL16(gb + ko, (char*)Bg[b] + wid * 1024);                                  \
    GL16(gu + ko, (char*)Bu[b] + wid * 1024);                                  \
  } while (0)
  f32x4 ag[4][2] = {}, au[4][2] = {};
  GU_STAGE(0, 0);
  GU_STAGE(1, 1);
  PIPE_SYNC(3);
  for (int t = 0; t < 32; ++t) {
    const int cb = t % 3;
    if (t + 2 < 32) GU_STAGE(t + 2, (t + 2) % 3);
    const unsigned short* As_ = As[cb];
    const unsigned short* Bg_ = Bg[cb];
    const unsigned short* Bu_ = Bu[cb];
    bf16x8 af[4], bgf[2], buf_[2];
#pragma unroll
    for (int i = 0; i < 4; ++i) af[i] = *(const bf16x8*)&As_[sw32(wm + i * 16 + fr, fg)];
#pragma unroll
    for (int j = 0; j < 2; ++j) {
      const int oB = sw32(wn + j * 16 + fr, fg);
      bgf[j] = *(const bf16x8*)&Bg_[oB];
      buf_[j] = *(const bf16x8*)&Bu_[oB];
    }
    SETPRIO(1);
#pragma unroll
    for (int i = 0; i < 4; ++i)
#pragma unroll
      for (int j = 0; j < 2; ++j) {
        ag[i][j] = MFMA16(af[i], bgf[j], ag[i][j]);
        au[i][j] = MFMA16(af[i], buf_[j], au[i][j]);
      }
    SETPRIO(0);
    if (t + 2 < 32) PIPE_SYNC(3);
    else if (t + 1 < 32) PIPE_SYNC(0);
  }
#undef GU_STAGE
  const int cr = fg * 4;
#pragma unroll
  for (int i = 0; i < 4; ++i)
#pragma unroll
    for (int j = 0; j < 2; ++j)
#pragma unroll
      for (int rr = 0; rr < 4; ++rr) {
        const int row = wm + i * 16 + cr + rr;  // tile-local
        const int col = n0 + wn + j * 16 + fr;
        const float gv = ag[i][j][rr];
        const float sg = gv / (1.f + __expf(-gv));  // silu
        act[(long)(padoff + m0 + row) * 3584 + col] = f2bf(sg * au[i][j][rr]);
      }
}

// MoE down GEMM + scatter: out[tok] += w * (act @ Wd^T)
// R8: BM=128, BN=256, 8 waves 2m x 4n, wave-tile 64x64 (2.0 MFMA/ds_read);
// 3-stage pipeline vmcnt(3); XCD chunk swizzle (nwg=1024, 128/XCD = 1 expert).
__global__ __launch_bounds__(512, 4) void down_kernel(const unsigned short* __restrict__ act,
                                                      const unsigned short* __restrict__ WD,
                                                      const int* __restrict__ tok,
                                                      const float* __restrict__ wgt,
                                                      const int* __restrict__ cnt,
                                                      float* __restrict__ out) {
  const int flat = blockIdx.x + 4 * (blockIdx.y + 32 * blockIdx.z);
  const int w = (flat & 7) * 128 + (flat >> 3);
  const int bx = w & 3, by = (w >> 2) & 31, e = w >> 7;
  const int cn = cnt[e];
  const int m0 = by * 128;
  if (m0 >= cn) return;
  int padoff = 0;
  for (int i = 0; i < e; ++i) padoff += (cnt[i] + 127) & ~127;
  const int n0 = bx * 256;
  __shared__ unsigned short As[3][4096], Bs[3][8192];
  const int tid = threadIdx.x, wid = tid >> 6, lane = tid & 63;
  const int wm = (wid >> 2) * 64, wn = (wid & 3) * 64;
  const int fr = lane & 15, fg = lane >> 4;
  const int srow = tid >> 2;                               // 0..127
  const int scol = (((tid & 3) ^ ((tid >> 3) & 3))) * 8;   // swizzled source chunk
  const unsigned short* ga = act + (long)(padoff + m0 + srow) * 3584 + scol;
  const unsigned short* gb = WD + (long)e * 1024 * 3584 + (long)(n0 + srow) * 3584 + scol;
#define DN_STAGE(s, b)                                                         \
  do {                                                                         \
    const int ko = (s) * 32;                                                   \
    GL16(ga + ko, (char*)As[b] + wid * 1024);                                  \
    GL16(gb + ko, (char*)Bs[b] + wid * 1024);                                  \
    GL16(gb + 128L * 3584 + ko, (char*)Bs[b] + 8192 + wid * 1024);             \
  } while (0)
  f32x4 acc[4][4] = {};
  DN_STAGE(0, 0);
  DN_STAGE(1, 1);
  PIPE_SYNC(3);
  for (int t = 0; t < 112; ++t) {
    const int cb = t % 3;
    if (t + 2 < 112) DN_STAGE(t + 2, (t + 2) % 3);
    const unsigned short* As_ = As[cb];
    const unsigned short* Bs_ = Bs[cb];
    bf16x8 af[4], bf_[4];
#pragma unroll
    for (int i = 0; i < 4; ++i) af[i] = *(const bf16x8*)&As_[sw32(wm + i * 16 + fr, fg)];
#pragma unroll
    for (int j = 0; j < 4; ++j) bf_[j] = *(const bf16x8*)&Bs_[sw32(wn + j * 16 + fr, fg)];
    SETPRIO(1);
#pragma unroll
    for (int i = 0; i < 4; ++i)
#pragma unroll
      for (int j = 0; j < 4; ++j)
        acc[i][j] = MFMA16(af[i], bf_[j], acc[i][j]);
    SETPRIO(0);
    if (t + 2 < 112) PIPE_SYNC(3);
    else if (t + 1 < 112) PIPE_SYNC(0);
  }
#undef DN_STAGE
  const int cr = fg * 4;
#pragma unroll
  for (int i = 0; i < 4; ++i)
#pragma unroll
    for (int rr = 0; rr < 4; ++rr) {
      const int lrow = m0 + wm + i * 16 + cr + rr;
      if (lrow < cn) {
        const int tk = tok[e * 4096 + lrow];
        const float wv_ = wgt[e * 4096 + lrow];
#pragma unroll
        for (int j = 0; j < 4; ++j)
          atomicAdd(&out[(long)tk * 1024 + n0 + wn + j * 16 + fr], wv_ * acc[i][j][rr]);
      }
    }
}

// ---------------------------------------------------------------------------
extern "C" void kernel_launch(void* const* d_in, const int* in_sizes, int n_in,
                              void* d_out, int out_size, void* d_ws, size_t ws_size,
                              hipStream_t stream) {
  (void)in_sizes; (void)n_in; (void)out_size;
  if (ws_size < WS_NEED) {
    fprintf(stderr, "kernel_launch: ws too small: %zu < %zu\n", ws_size, (size_t)WS_NEED);
  }
  const float* x    = (const float*)d_in[0];
  const float* n1s  = (const float*)d_in[1];
  const float* n2s  = (const float*)d_in[2];
  const float* wq   = (const float*)d_in[3];
  const float* wk   = (const float*)d_in[4];
  const float* wv   = (const float*)d_in[5];
  const float* wo   = (const float*)d_in[6];
  const float* wrt  = (const float*)d_in[7];
  const float* wg   = (const float*)d_in[8];
  const float* wu   = (const float*)d_in[9];
  const float* wd   = (const float*)d_in[10];
  float* out = (float*)d_out;
  char* W = (char*)d_ws;

  unsigned short* WQH = (unsigned short*)(W + O_WQKVT_HI);
  unsigned short* WQL = (unsigned short*)(W + O_WQKVT_LO);
  unsigned short* WOH = (unsigned short*)(W + O_WOT_HI);
  unsigned short* WOL = (unsigned short*)(W + O_WOT_LO);
  unsigned short* WGT = (unsigned short*)(W + O_WGT);
  unsigned short* WUT = (unsigned short*)(W + O_WUT);
  unsigned short* WDT = (unsigned short*)(W + O_WDT);
  unsigned short* H2  = (unsigned short*)(W + O_H2);
  int* TOK    = (int*)(W + O_TOK);
  float* WGTL = (float*)(W + O_WGTL);
  int* CNT    = (int*)(W + O_CNT);
  unsigned short* HSH = (unsigned short*)(W + O_HSHI);
  unsigned short* HSL = (unsigned short*)(W + O_HSLO);
  float* QKV = (float*)(W + O_QKV);
  unsigned short* QHI = (unsigned short*)(W + O_QHI);
  unsigned short* QLO = (unsigned short*)(W + O_QLO);
  unsigned short* KHI = (unsigned short*)(W + O_KHI);
  unsigned short* KLO = (unsigned short*)(W + O_KLO);
  unsigned short* VTH = (unsigned short*)(W + O_VTH);
  unsigned short* VTL = (unsigned short*)(W + O_VTL);
  unsigned short* AHI = (unsigned short*)(W + O_AHI);
  unsigned short* ALO = (unsigned short*)(W + O_ALO);
  float* XATTN = (float*)(W + O_XATTN);
  unsigned short* ACT = (unsigned short*)(W + O_ACT);

  zero_cnt_kernel<<<1, 64, 0, stream>>>(CNT);
  // RMSNorm1 -> split hs
  rmsnorm_kernel<<<4096, 256, 0, stream>>>(x, n1s, HSH, HSL);
  // weight transposes (per call; bf16 [N][K] layouts)
  transpose_cvt_split<<<dim3(16, 16, 1), 256, 0, stream>>>(wq, WQH, WQL, 1024, 1024);
  transpose_cvt_split<<<dim3(4, 16, 1), 256, 0, stream>>>(wk, WQH + 1024L * 1024, WQL + 1024L * 1024, 1024, 256);
  transpose_cvt_split<<<dim3(4, 16, 1), 256, 0, stream>>>(wv, WQH + 1280L * 1024, WQL + 1280L * 1024, 1024, 256);
  transpose_cvt_split<<<dim3(16, 16, 1), 256, 0, stream>>>(wo, WOH, WOL, 1024, 1024);
  transpose_cvt<<<dim3(56, 16, 8), 256, 0, stream>>>(wg, WGT, 1024, 3584, 1024L * 3584, 3584L * 1024);
  transpose_cvt<<<dim3(56, 16, 8), 256, 0, stream>>>(wu, WUT, 1024, 3584, 1024L * 3584, 3584L * 1024);
  transpose_cvt<<<dim3(16, 56, 8), 256, 0, stream>>>(wd, WDT, 3584, 1024, 3584L * 1024, 1024L * 3584);
  // QKV projection (split GEMM, f32 out)
  gemm_split<<<dim3(12, 32, 1), 256, 0, stream>>>(HSH, HSL, WQH, WQL, nullptr, QKV, 4096, 1536, 1024);
  // RoPE + split; V transpose + split
  rope_kernel<<<4096, 256, 0, stream>>>(QKV, QHI, QLO, KHI, KLO);
  vt_split_kernel<<<dim3(32, 4, 2), 256, 0, stream>>>(QKV, VTH, VTL);
  // attention
  attn_kernel<<<dim3(32, 16, 2), 256, 0, stream>>>(QHI, QLO, KHI, KLO, VTH, VTL, AHI, ALO);
  // out projection + residual
  gemm_split<<<dim3(8, 32, 1), 256, 0, stream>>>(AHI, ALO, WOH, WOL, x, XATTN, 4096, 1024, 1024);
  // RMSNorm2 -> h2 (bf16, for experts)
  rmsnorm_kernel<<<4096, 256, 0, stream>>>(XATTN, n2s, H2, nullptr);
  // router (f32 path) -> logits into d_out tail + routing lists
  router_kernel<<<4096, 256, 0, stream>>>(XATTN, n2s, wrt, out + 4194304, TOK, WGTL, CNT);
  // init decoder_output with residual, then scatter MoE into it
  init_out_kernel<<<4096, 256, 0, stream>>>(XATTN, out);
  gateup_kernel<<<dim3(28, 32, 8), 512, 0, stream>>>(H2, WGT, WUT, TOK, CNT, ACT);
  down_kernel<<<dim3(4, 32, 8), 512, 0, stream>>>(ACT, WDT, TOK, WGTL, CNT, out);
}

// Round 9
// 679.888 us; speedup vs baseline: 1.0503x; 1.0503x over previous
//
#include <hip/hip_runtime.h>
#include <hip/hip_bf16.h>
#include <cstdio>

// ---------------------------------------------------------------------------
// MixtralTransformerDecoder: B=2 S=2048 H=1024 NQ=16 NKV=4 HD=64 I=3584 E=8
// TOP_K=2, sliding window 512.
// Split-bf16 (hi+lo) MFMA upstream of the router; plain bf16 MFMA for experts.
// R9: down reverted to R6-exact (BN=128 / wave 64x32 / 2048 blocks — twice
// confirmed best). rmsnorm2 + router + init_out fused into one kernel (one
// XATTN read instead of three). gateup/gemm_split/attn at R6 config.
// ---------------------------------------------------------------------------

typedef __bf16 bf16x8 __attribute__((ext_vector_type(8)));
typedef float f32x4 __attribute__((ext_vector_type(4)));

#define MFMA16(a, b, c) __builtin_amdgcn_mfma_f32_16x16x32_bf16((a), (b), (c), 0, 0, 0)
#define GL16(g, l)                                                             \
  __builtin_amdgcn_global_load_lds(                                            \
      (const __attribute__((address_space(1))) void*)(g),                      \
      (__attribute__((address_space(3))) void*)(l), 16, 0, 0)
#define WAIT_VM0() asm volatile("s_waitcnt vmcnt(0)" ::: "memory")
#define SETPRIO(n) __builtin_amdgcn_s_setprio(n)
// counted-vmcnt + raw barrier + compiler fence (T4; __syncthreads would drain)
#define PIPE_SYNC(n)                                                           \
  do {                                                                         \
    asm volatile("s_waitcnt vmcnt(" #n ")" ::: "memory");                      \
    __builtin_amdgcn_s_barrier();                                              \
    asm volatile("" ::: "memory");                                             \
  } while (0)

__device__ __forceinline__ unsigned short f2bf(float f) {
  unsigned u = __builtin_bit_cast(unsigned, f);
  u += 0x7fffu + ((u >> 16) & 1u);
  return (unsigned short)(u >> 16);
}
__device__ __forceinline__ float bf2f(unsigned short h) {
  unsigned u = ((unsigned)h) << 16;
  return __builtin_bit_cast(float, u);
}
// swizzled element offset for [row][32 bf16] LDS tiles (64B rows, 4 chunks)
__device__ __forceinline__ int sw32(int row, int chunk) {
  return row * 32 + ((chunk ^ ((row >> 1) & 3)) * 8);
}

// ---------------------------------------------------------------------------
// Workspace layout (bytes)
// ---------------------------------------------------------------------------
static constexpr size_t O_WQKVT_HI = 0;                           // [1536][1024] bf16
static constexpr size_t SZ_WQKVT   = 1536UL * 1024 * 2;
static constexpr size_t O_WQKVT_LO = O_WQKVT_HI + SZ_WQKVT;
static constexpr size_t O_WOT_HI   = O_WQKVT_LO + SZ_WQKVT;       // [1024][1024] bf16
static constexpr size_t SZ_WOT     = 1024UL * 1024 * 2;
static constexpr size_t O_WOT_LO   = O_WOT_HI + SZ_WOT;
static constexpr size_t O_WGT      = O_WOT_LO + SZ_WOT;           // [8][3584][1024] bf16
static constexpr size_t SZ_WE      = 8UL * 3584 * 1024 * 2;
static constexpr size_t O_WUT      = O_WGT + SZ_WE;
static constexpr size_t O_WDT      = O_WUT + SZ_WE;               // [8][1024][3584] bf16
static constexpr size_t O_H2       = O_WDT + SZ_WE;               // [4096][1024] bf16
static constexpr size_t SZ_BF_TH   = 4096UL * 1024 * 2;
static constexpr size_t O_TOK      = O_H2 + SZ_BF_TH;             // [8][4096] i32
static constexpr size_t O_WGTL     = O_TOK + 8UL * 4096 * 4;      // [8][4096] f32
static constexpr size_t O_CNT      = O_WGTL + 8UL * 4096 * 4;     // [8] i32
static constexpr size_t O_DYN      = O_CNT + 256;
// DYN region (dead before MoE; ACT aliases its head)
static constexpr size_t O_HSHI  = O_DYN;
static constexpr size_t O_HSLO  = O_HSHI + SZ_BF_TH;
static constexpr size_t O_QKV   = O_HSLO + SZ_BF_TH;              // [4096][1536] f32
static constexpr size_t O_QHI   = O_QKV + 4096UL * 1536 * 4;      // [2][16][2048][64] bf16
static constexpr size_t O_QLO   = O_QHI + SZ_BF_TH;
static constexpr size_t O_KHI   = O_QLO + SZ_BF_TH;               // [2][4][2048][64] bf16
static constexpr size_t SZ_BF_T256 = 4096UL * 256 * 2;
static constexpr size_t O_KLO   = O_KHI + SZ_BF_T256;
static constexpr size_t O_VTH   = O_KLO + SZ_BF_T256;             // [2][4][64][2048] bf16
static constexpr size_t O_VTL   = O_VTH + SZ_BF_T256;
static constexpr size_t O_AHI   = O_VTL + SZ_BF_T256;             // [4096][1024] bf16
static constexpr size_t O_ALO   = O_AHI + SZ_BF_TH;
static constexpr size_t O_XATTN = O_ALO + SZ_BF_TH;               // [4096][1024] f32
static constexpr size_t O_END   = O_XATTN + 4096UL * 1024 * 4;
static constexpr size_t O_ACT   = O_DYN;   // [<=9208][3584] bf16 alias (66MB, before XATTN)
static constexpr size_t WS_NEED = O_END;

// ---------------------------------------------------------------------------
// small kernels
// ---------------------------------------------------------------------------
__global__ void zero_cnt_kernel(int* c) {
  if (threadIdx.x < 8) c[threadIdx.x] = 0;
}

// RMSNorm: x[4096][1024] f32 -> hi (+ optional lo) bf16
__global__ __launch_bounds__(256) void rmsnorm_kernel(const float* __restrict__ x,
                                                      const float* __restrict__ scale,
                                                      unsigned short* __restrict__ hi,
                                                      unsigned short* __restrict__ lo) {
  const int t = blockIdx.x, tid = threadIdx.x;
  const float4 v = *(const float4*)&x[(long)t * 1024 + tid * 4];
  float ss = v.x * v.x + v.y * v.y + v.z * v.z + v.w * v.w;
#pragma unroll
  for (int off = 32; off >= 1; off >>= 1) ss += __shfl_down(ss, off);
  __shared__ float red[4];
  if ((tid & 63) == 0) red[tid >> 6] = ss;
  __syncthreads();
  const float r = rsqrtf((red[0] + red[1] + red[2] + red[3]) * (1.0f / 1024.0f) + 1e-5f);
  const float4 sc = *(const float4*)&scale[tid * 4];
  float o[4] = {v.x * r * sc.x, v.y * r * sc.y, v.z * r * sc.z, v.w * r * sc.w};
  ushort4 hh, ll;
  unsigned short* hp = (unsigned short*)&hh;
  unsigned short* lp = (unsigned short*)&ll;
#pragma unroll
  for (int i = 0; i < 4; ++i) {
    hp[i] = f2bf(o[i]);
    lp[i] = f2bf(o[i] - bf2f(hp[i]));
  }
  *(ushort4*)&hi[(long)t * 1024 + tid * 4] = hh;
  if (lo) *(ushort4*)&lo[(long)t * 1024 + tid * 4] = ll;
}

// transpose+convert: src f32 [R][C] -> dst bf16 [C][R]
__global__ __launch_bounds__(256) void transpose_cvt(const float* __restrict__ src,
                                                     unsigned short* __restrict__ dst,
                                                     int R, int C, long zsrc, long zdst) {
  src += (long)blockIdx.z * zsrc;
  dst += (long)blockIdx.z * zdst;
  const int c0 = blockIdx.x * 64, r0 = blockIdx.y * 64, tid = threadIdx.x;
  __shared__ float tb[64][65];
#pragma unroll
  for (int p = 0; p < 4; ++p) {
    const int r = p * 16 + (tid >> 4), c = (tid & 15) * 4;
    const float4 v = *(const float4*)&src[(long)(r0 + r) * C + c0 + c];
    tb[c + 0][r] = v.x; tb[c + 1][r] = v.y; tb[c + 2][r] = v.z; tb[c + 3][r] = v.w;
  }
  __syncthreads();
  const int dr = tid >> 2, s0 = (tid & 3) * 16;
  __align__(16) unsigned short tmp[16];
#pragma unroll
  for (int i = 0; i < 16; ++i) tmp[i] = f2bf(tb[dr][s0 + i]);
  const long o = (long)(c0 + dr) * R + r0 + s0;
  *(uint4*)&dst[o] = *(const uint4*)&tmp[0];
  *(uint4*)&dst[o + 8] = *(const uint4*)&tmp[8];
}

// transpose+convert+split: src f32 [R][C] -> hi,lo bf16 [C][R]
__global__ __launch_bounds__(256) void transpose_cvt_split(const float* __restrict__ src,
                                                           unsigned short* __restrict__ dh,
                                                           unsigned short* __restrict__ dl,
                                                           int R, int C) {
  const int c0 = blockIdx.x * 64, r0 = blockIdx.y * 64, tid = threadIdx.x;
  __shared__ float tb[64][65];
#pragma unroll
  for (int p = 0; p < 4; ++p) {
    const int r = p * 16 + (tid >> 4), c = (tid & 15) * 4;
    const float4 v = *(const float4*)&src[(long)(r0 + r) * C + c0 + c];
    tb[c + 0][r] = v.x; tb[c + 1][r] = v.y; tb[c + 2][r] = v.z; tb[c + 3][r] = v.w;
  }
  __syncthreads();
  const int dr = tid >> 2, s0 = (tid & 3) * 16;
  __align__(16) unsigned short th[16], tl[16];
#pragma unroll
  for (int i = 0; i < 16; ++i) {
    const float f = tb[dr][s0 + i];
    th[i] = f2bf(f);
    tl[i] = f2bf(f - bf2f(th[i]));
  }
  const long o = (long)(c0 + dr) * R + r0 + s0;
  *(uint4*)&dh[o] = *(const uint4*)&th[0];
  *(uint4*)&dh[o + 8] = *(const uint4*)&th[8];
  *(uint4*)&dl[o] = *(const uint4*)&tl[0];
  *(uint4*)&dl[o + 8] = *(const uint4*)&tl[8];
}

// ---------------------------------------------------------------------------
// split-bf16 GEMM: C[M][N] = (Ahi+Alo)[M][K] @ (Bhi+Blo)[N][K]^T (+resid)
// 128x128 tile, BK=32, dbuf prefetch + swizzle + setprio (R6 form).
// ---------------------------------------------------------------------------
__global__ __launch_bounds__(256) void gemm_split(const unsigned short* __restrict__ Ahi,
                                                  const unsigned short* __restrict__ Alo,
                                                  const unsigned short* __restrict__ Bhi,
                                                  const unsigned short* __restrict__ Blo,
                                                  const float* __restrict__ resid,
                                                  float* __restrict__ C,
                                                  int M, int N, int K) {
  __shared__ unsigned short Ash[2][4096], Asl[2][4096], Bsh[2][4096], Bsl[2][4096];
  const int tid = threadIdx.x, wid = tid >> 6, lane = tid & 63;
  const int m0 = blockIdx.y * 128, n0 = blockIdx.x * 128;
  const int wm = (wid >> 1) * 64, wn = (wid & 1) * 64;
  const int fr = lane & 15, fg = lane >> 4;
  const int srow = tid >> 2;
  const int scol = (((tid & 3) ^ ((tid >> 3) & 3))) * 8;  // swizzled source chunk
  const long aoff = (long)(m0 + srow) * K + scol;
  const long boff = (long)(n0 + srow) * K + scol;
  const long h64 = 64L * K;
  char* a0 = (char*)Ash[0] + wid * 1024; char* a1 = (char*)Ash[1] + wid * 1024;
  char* al0 = (char*)Asl[0] + wid * 1024; char* al1 = (char*)Asl[1] + wid * 1024;
  char* b0 = (char*)Bsh[0] + wid * 1024; char* b1 = (char*)Bsh[1] + wid * 1024;
  char* bl0 = (char*)Bsl[0] + wid * 1024; char* bl1 = (char*)Bsl[1] + wid * 1024;
#define GS_STAGE(koff, pah_, pal_, pbh_, pbl_)                                 \
  do {                                                                         \
    GL16(Ahi + aoff + (koff), (pah_));                                         \
    GL16(Ahi + aoff + h64 + (koff), (pah_) + 4096);                            \
    GL16(Alo + aoff + (koff), (pal_));                                         \
    GL16(Alo + aoff + h64 + (koff), (pal_) + 4096);                            \
    GL16(Bhi + boff + (koff), (pbh_));                                         \
    GL16(Bhi + boff + h64 + (koff), (pbh_) + 4096);                            \
    GL16(Blo + boff + (koff), (pbl_));                                         \
    GL16(Blo + boff + h64 + (koff), (pbl_) + 4096);                            \
  } while (0)
  f32x4 acc[4][4] = {};
  GS_STAGE(0, a0, al0, b0, bl0);
  WAIT_VM0();
  __syncthreads();
  int cur = 0;
  for (int k0 = 0; k0 < K; k0 += 32) {
    const int kn = k0 + 32;
    if (kn < K) {
      if (cur) GS_STAGE(kn, a0, al0, b0, bl0);
      else     GS_STAGE(kn, a1, al1, b1, bl1);
    }
    const unsigned short* As_ = Ash[cur];
    const unsigned short* Al_ = Asl[cur];
    const unsigned short* Bs_ = Bsh[cur];
    const unsigned short* Bl_ = Bsl[cur];
    bf16x8 ah[4], al[4], bh[4], bl[4];
#pragma unroll
    for (int i = 0; i < 4; ++i) {
      const int oA = sw32(wm + i * 16 + fr, fg);
      const int oB = sw32(wn + i * 16 + fr, fg);
      ah[i] = *(const bf16x8*)&As_[oA];
      al[i] = *(const bf16x8*)&Al_[oA];
      bh[i] = *(const bf16x8*)&Bs_[oB];
      bl[i] = *(const bf16x8*)&Bl_[oB];
    }
    SETPRIO(1);
#pragma unroll
    for (int i = 0; i < 4; ++i)
#pragma unroll
      for (int j = 0; j < 4; ++j) {
        acc[i][j] = MFMA16(al[i], bh[j], acc[i][j]);
        acc[i][j] = MFMA16(ah[i], bl[j], acc[i][j]);
        acc[i][j] = MFMA16(ah[i], bh[j], acc[i][j]);
      }
    SETPRIO(0);
    WAIT_VM0();
    __syncthreads();
    cur ^= 1;
  }
#undef GS_STAGE
  const int cr = fg * 4;
#pragma unroll
  for (int i = 0; i < 4; ++i)
#pragma unroll
    for (int j = 0; j < 4; ++j)
#pragma unroll
      for (int rr = 0; rr < 4; ++rr) {
        const int row = m0 + wm + i * 16 + cr + rr;
        const int col = n0 + wn + j * 16 + fr;
        float v = acc[i][j][rr];
        if (resid) v += resid[(long)row * N + col];
        C[(long)row * N + col] = v;
      }
}

// ---------------------------------------------------------------------------
// RoPE + split: qkv f32 [4096][1536] -> Qhi/Qlo (scaled 1/8), Khi/Klo
// ---------------------------------------------------------------------------
__global__ __launch_bounds__(256) void rope_kernel(const float* __restrict__ qkv,
                                                   unsigned short* __restrict__ Qh,
                                                   unsigned short* __restrict__ Ql,
                                                   unsigned short* __restrict__ Kh,
                                                   unsigned short* __restrict__ Kl) {
  const int t = blockIdx.x, b = t >> 11, s = t & 2047;
  const float* src = qkv + (long)t * 1536;
  for (int task = threadIdx.x; task < 640; task += 256) {
    const int head = task >> 5, p = task & 31;
    const float* hp = src + head * 64;
    const float inv = (float)exp2(-(double)p * 0.4152410118609203);  // 10000^(-p/32)
    const float f = (float)s * inv;
    float sn, cs;
    sincosf(f, &sn, &cs);
    const float x0 = hp[2 * p], x1 = hp[2 * p + 1], xa = hp[p], xb = hp[32 + p];
    float o0 = x0 * cs - xb * sn;
    float o1 = x1 * cs + xa * sn;
    unsigned short *dh, *dl;
    long base;
    if (head < 16) {
      o0 *= 0.125f; o1 *= 0.125f;  // fold 1/sqrt(64) into Q
      base = ((long)(b * 16 + head) * 2048 + s) * 64;
      dh = Qh; dl = Ql;
    } else {
      base = ((long)(b * 4 + (head - 16)) * 2048 + s) * 64;
      dh = Kh; dl = Kl;
    }
    unsigned short h0 = f2bf(o0);
    dh[base + 2 * p] = h0; dl[base + 2 * p] = f2bf(o0 - bf2f(h0));
    unsigned short h1 = f2bf(o1);
    dh[base + 2 * p + 1] = h1; dl[base + 2 * p + 1] = f2bf(o1 - bf2f(h1));
  }
}

// V transpose+split: -> Vth/Vtl [2][4][64][2048] bf16
__global__ __launch_bounds__(256) void vt_split_kernel(const float* __restrict__ qkv,
                                                       unsigned short* __restrict__ Vh,
                                                       unsigned short* __restrict__ Vl) {
  const int st = blockIdx.x * 64, g = blockIdx.y, b = blockIdx.z, tid = threadIdx.x;
  __shared__ float tb[64][65];
  const float* src = qkv + (long)(b * 2048 + st) * 1536 + 1280 + g * 64;
#pragma unroll
  for (int p = 0; p < 4; ++p) {
    const int r = p * 16 + (tid >> 4), c = (tid & 15) * 4;
    const float4 v = *(const float4*)&src[(long)r * 1536 + c];
    tb[c + 0][r] = v.x; tb[c + 1][r] = v.y; tb[c + 2][r] = v.z; tb[c + 3][r] = v.w;
  }
  __syncthreads();
  const int dr = tid >> 2, s0 = (tid & 3) * 16;
  __align__(16) unsigned short hh[16], ll[16];
#pragma unroll
  for (int i = 0; i < 16; ++i) {
    const float f = tb[dr][s0 + i];
    hh[i] = f2bf(f);
    ll[i] = f2bf(f - bf2f(hh[i]));
  }
  const long dst = ((long)(b * 4 + g) * 64 + dr) * 2048 + st + s0;
  *(uint4*)&Vh[dst] = *(const uint4*)&hh[0];
  *(uint4*)&Vh[dst + 8] = *(const uint4*)&hh[8];
  *(uint4*)&Vl[dst] = *(const uint4*)&ll[0];
  *(uint4*)&Vl[dst + 8] = *(const uint4*)&ll[8];
}

// ---------------------------------------------------------------------------
// Flash attention, split-bf16 MFMA, sliding window 512, causal (R6 form).
// ---------------------------------------------------------------------------
__global__ __launch_bounds__(256) void attn_kernel(const unsigned short* __restrict__ Qh,
                                                   const unsigned short* __restrict__ Ql,
                                                   const unsigned short* __restrict__ Kh,
                                                   const unsigned short* __restrict__ Kl,
                                                   const unsigned short* __restrict__ Vh,
                                                   const unsigned short* __restrict__ Vl,
                                                   unsigned short* __restrict__ Ohi,
                                                   unsigned short* __restrict__ Olo) {
  const int qt = blockIdx.x, h = blockIdx.y, b = blockIdx.z, g = h >> 2;
  const int q0 = qt * 64, tid = threadIdx.x, wid = tid >> 6, lane = tid & 63;
  const int fr = lane & 15, fg = lane >> 4;
  __shared__ unsigned short Ksh[2][2048], Ksl[2][2048];  // [32 keys][64 d]
  __shared__ unsigned short Vsh[2][2048], Vsl[2][2048];  // [64 d][32 keys]
  __shared__ unsigned short Ph[4][512], Pl[4][512];      // per-wave [16][32]

  const long qoff = ((long)(b * 16 + h) * 2048 + q0 + wid * 16 + fr) * 64;
  bf16x8 qh[2], ql[2];
  qh[0] = *(const bf16x8*)&Qh[qoff + fg * 8];
  qh[1] = *(const bf16x8*)&Qh[qoff + 32 + fg * 8];
  ql[0] = *(const bf16x8*)&Ql[qoff + fg * 8];
  ql[1] = *(const bf16x8*)&Ql[qoff + 32 + fg * 8];

  f32x4 o[4] = {};
  float mrow[4], lrow[4];
#pragma unroll
  for (int rr = 0; rr < 4; ++rr) { mrow[rr] = -1e30f; lrow[rr] = 0.f; }

  const int jmin = (q0 >= 511) ? (q0 - 511) : 0;
  const int jt0 = jmin & ~31;
  const long kbase = ((long)(b * 4 + g) * 2048) * 64;
  const long vbase = ((long)(b * 4 + g) * 64) * 2048;
  const int srK = tid >> 3;                                  // 0..31
  const int scK = (((tid & 7) ^ (srK & 7))) * 8;             // swizzled K source chunk
  const int srV = tid >> 2;                                  // 0..63
  const int scV = (((tid & 3) ^ ((srV >> 1) & 3))) * 8;      // swizzled V source chunk
  char* kh0 = (char*)Ksh[0] + wid * 1024; char* kh1 = (char*)Ksh[1] + wid * 1024;
  char* kl0 = (char*)Ksl[0] + wid * 1024; char* kl1 = (char*)Ksl[1] + wid * 1024;
  char* vh0 = (char*)Vsh[0] + wid * 1024; char* vh1 = (char*)Vsh[1] + wid * 1024;
  char* vl0 = (char*)Vsl[0] + wid * 1024; char* vl1 = (char*)Vsl[1] + wid * 1024;
#define ATTN_STAGE(jt_, kh_, kl_, vh_, vl_)                                    \
  do {                                                                         \
    const long ko = kbase + (long)((jt_) + srK) * 64 + scK;                    \
    GL16(Kh + ko, (kh_));                                                      \
    GL16(Kl + ko, (kl_));                                                      \
    const long vo = vbase + (long)srV * 2048 + (jt_) + scV;                    \
    GL16(Vh + vo, (vh_));                                                      \
    GL16(Vl + vo, (vl_));                                                      \
  } while (0)

  ATTN_STAGE(jt0, kh0, kl0, vh0, vl0);
  WAIT_VM0();
  __syncthreads();
  int cur = 0;
  for (int jt = jt0; jt < q0 + 64; jt += 32) {
    const int jn = jt + 32;
    if (jn < q0 + 64) {
      if (cur) ATTN_STAGE(jn, kh0, kl0, vh0, vl0);
      else     ATTN_STAGE(jn, kh1, kl1, vh1, vl1);
    }
    const unsigned short* KH = Ksh[cur];
    const unsigned short* KL = Ksl[cur];
    const unsigned short* VH = Vsh[cur];
    const unsigned short* VL = Vsl[cur];

    // ---- QK^T (3-term split); K rows 128B -> chunk ^= row&7 ----
    f32x4 sf[2] = {};
#pragma unroll
    for (int cf = 0; cf < 2; ++cf)
#pragma unroll
      for (int dc = 0; dc < 2; ++dc) {
        const int row = cf * 16 + fr;
        const int off = row * 64 + (((dc * 4 + fg) ^ (row & 7)) * 8);
        const bf16x8 kh = *(const bf16x8*)&KH[off];
        const bf16x8 kl = *(const bf16x8*)&KL[off];
        sf[cf] = MFMA16(ql[dc], kh, sf[cf]);
        sf[cf] = MFMA16(qh[dc], kl, sf[cf]);
        sf[cf] = MFMA16(qh[dc], kh, sf[cf]);
      }

    // ---- mask + online softmax ----
    float sv[2][4];
#pragma unroll
    for (int cf = 0; cf < 2; ++cf) {
      const int j = jt + cf * 16 + fr;
#pragma unroll
      for (int rr = 0; rr < 4; ++rr) {
        const int q = q0 + wid * 16 + fg * 4 + rr;
        const bool ok = (j <= q) && (j >= q - 511);
        sv[cf][rr] = ok ? sf[cf][rr] : -1e30f;
      }
    }
    float scl_[4];
#pragma unroll
    for (int rr = 0; rr < 4; ++rr) {
      float mx = fmaxf(sv[0][rr], sv[1][rr]);
      mx = fmaxf(mx, __shfl_xor(mx, 1));
      mx = fmaxf(mx, __shfl_xor(mx, 2));
      mx = fmaxf(mx, __shfl_xor(mx, 4));
      mx = fmaxf(mx, __shfl_xor(mx, 8));
      const float mn = fmaxf(mrow[rr], mx);
      scl_[rr] = __expf(mrow[rr] - mn);
      mrow[rr] = mn;
    }
    float ps[2][4], rs[4] = {0.f, 0.f, 0.f, 0.f};
#pragma unroll
    for (int cf = 0; cf < 2; ++cf)
#pragma unroll
      for (int rr = 0; rr < 4; ++rr) {
        const float p = (sv[cf][rr] > -1e29f) ? __expf(sv[cf][rr] - mrow[rr]) : 0.f;
        ps[cf][rr] = p;
        rs[rr] += p;
      }
#pragma unroll
    for (int rr = 0; rr < 4; ++rr) {
      float r = rs[rr];
      r += __shfl_xor(r, 1);
      r += __shfl_xor(r, 2);
      r += __shfl_xor(r, 4);
      r += __shfl_xor(r, 8);
      lrow[rr] = lrow[rr] * scl_[rr] + r;
      o[0][rr] *= scl_[rr]; o[1][rr] *= scl_[rr];
      o[2][rr] *= scl_[rr]; o[3][rr] *= scl_[rr];
    }
    // ---- P -> LDS (split, swizzled [16 q][32 k]) ----
#pragma unroll
    for (int cf = 0; cf < 2; ++cf)
#pragma unroll
      for (int rr = 0; rr < 4; ++rr) {
        const int q = fg * 4 + rr, k = cf * 16 + fr;
        const int idx = q * 32 + (((k >> 3) ^ ((q >> 1) & 3)) * 8) + (k & 7);
        const unsigned short hb = f2bf(ps[cf][rr]);
        Ph[wid][idx] = hb;
        Pl[wid][idx] = f2bf(ps[cf][rr] - bf2f(hb));
      }
    const int pro = sw32(fr, fg);
    const bf16x8 pah = *(const bf16x8*)&Ph[wid][pro];
    const bf16x8 pal = *(const bf16x8*)&Pl[wid][pro];
    // ---- PV (3-term split); V rows 64B -> sw32 ----
#pragma unroll
    for (int df = 0; df < 4; ++df) {
      const int vo = sw32(df * 16 + fr, fg);
      const bf16x8 vh = *(const bf16x8*)&VH[vo];
      const bf16x8 vl = *(const bf16x8*)&VL[vo];
      o[df] = MFMA16(pal, vh, o[df]);
      o[df] = MFMA16(pah, vl, o[df]);
      o[df] = MFMA16(pah, vh, o[df]);
    }
    WAIT_VM0();
    __syncthreads();
    cur ^= 1;
  }
#undef ATTN_STAGE
  // ---- epilogue: normalize, split, store ----
#pragma unroll
  for (int df = 0; df < 4; ++df)
#pragma unroll
    for (int rr = 0; rr < 4; ++rr) {
      const int q = q0 + wid * 16 + fg * 4 + rr;
      const float v = o[df][rr] / lrow[rr];
      const long oi = ((long)(b * 2048 + q)) * 1024 + h * 64 + df * 16 + fr;
      const unsigned short hb = f2bf(v);
      Ohi[oi] = hb;
      Olo[oi] = f2bf(v - bf2f(hb));
    }
}

// ---------------------------------------------------------------------------
// Fused epilogue: residual init (out = xattn), RMSNorm2 -> H2 bf16,
// router logits (f32) -> d_out tail, top-2 + compaction lists.
// One XATTN read instead of three kernels' worth.
// ---------------------------------------------------------------------------
__global__ __launch_bounds__(256) void router_fused_kernel(const float* __restrict__ xattn,
                                                           const float* __restrict__ scale,
                                                           const float* __restrict__ wr,
                                                           float* __restrict__ logits,
                                                           unsigned short* __restrict__ h2,
                                                           float* __restrict__ outres,
                                                           int* __restrict__ tok,
                                                           float* __restrict__ wgt,
                                                           int* __restrict__ cnt) {
  const int t = blockIdx.x, tid = threadIdx.x;
  const float4 v = *(const float4*)&xattn[(long)t * 1024 + tid * 4];
  *(float4*)&outres[(long)t * 1024 + tid * 4] = v;  // residual init of decoder_output
  float ss = v.x * v.x + v.y * v.y + v.z * v.z + v.w * v.w;
#pragma unroll
  for (int off = 32; off >= 1; off >>= 1) ss += __shfl_down(ss, off);
  __shared__ float red[4];
  __shared__ float redE[4][8];
  __shared__ float lg[8];
  if ((tid & 63) == 0) red[tid >> 6] = ss;
  __syncthreads();
  const float r = rsqrtf((red[0] + red[1] + red[2] + red[3]) * (1.0f / 1024.0f) + 1e-5f);
  const float4 sc = *(const float4*)&scale[tid * 4];
  const float hv[4] = {v.x * r * sc.x, v.y * r * sc.y, v.z * r * sc.z, v.w * r * sc.w};
  // H2 row (bit-identical to the old rmsnorm_kernel hi-path)
  ushort4 hh;
  unsigned short* hp = (unsigned short*)&hh;
#pragma unroll
  for (int i = 0; i < 4; ++i) hp[i] = f2bf(hv[i]);
  *(ushort4*)&h2[(long)t * 1024 + tid * 4] = hh;
  // router logits
  float part[8];
#pragma unroll
  for (int e = 0; e < 8; ++e) part[e] = 0.f;
#pragma unroll
  for (int i = 0; i < 4; ++i) {
    const float* w = &wr[(long)(tid * 4 + i) * 8];
#pragma unroll
    for (int e = 0; e < 8; ++e) part[e] = fmaf(hv[i], w[e], part[e]);
  }
#pragma unroll
  for (int off = 32; off >= 1; off >>= 1)
#pragma unroll
    for (int e = 0; e < 8; ++e) part[e] += __shfl_down(part[e], off);
  if ((tid & 63) == 0)
#pragma unroll
    for (int e = 0; e < 8; ++e) redE[tid >> 6][e] = part[e];
  __syncthreads();
  if (tid < 8) {
    const float l8 = redE[0][tid] + redE[1][tid] + redE[2][tid] + redE[3][tid];
    lg[tid] = l8;
    logits[(long)t * 8 + tid] = l8;
  }
  __syncthreads();
  if (tid == 0) {
    float mx = lg[0];
#pragma unroll
    for (int e = 1; e < 8; ++e) mx = fmaxf(mx, lg[e]);
    float p[8];
#pragma unroll
    for (int e = 0; e < 8; ++e) p[e] = __expf(lg[e] - mx);
    int i1 = 0;
#pragma unroll
    for (int e = 1; e < 8; ++e) if (p[e] > p[i1]) i1 = e;
    int i2 = (i1 == 0) ? 1 : 0;
#pragma unroll
    for (int e = 0; e < 8; ++e) if (e != i2 && e != i1 && p[e] > p[i2]) i2 = e;
    const float wsum = p[i1] + p[i2];
    const float w1 = p[i1] / wsum, w2 = p[i2] / wsum;
    const int pos1 = atomicAdd(&cnt[i1], 1);
    tok[i1 * 4096 + pos1] = t; wgt[i1 * 4096 + pos1] = w1;
    const int pos2 = atomicAdd(&cnt[i2], 1);
    tok[i2 * 4096 + pos2] = t; wgt[i2 * 4096 + pos2] = w2;
  }
}

// ---------------------------------------------------------------------------
// MoE gate+up fused GEMM (gathered A): act = silu(h2@Wg^T) * (h2@Wu^T), bf16
// R3 structure: 512 threads (8 waves, 2Mx4N), 3-stage pipeline, vmcnt(3).
// + XCD chunk swizzle.
// ---------------------------------------------------------------------------
__global__ __launch_bounds__(512, 4) void gateup_kernel(const unsigned short* __restrict__ H2,
                                                        const unsigned short* __restrict__ WG,
                                                        const unsigned short* __restrict__ WU,
                                                        const int* __restrict__ tok,
                                                        const int* __restrict__ cnt,
                                                        unsigned short* __restrict__ act) {
  // XCD chunk swizzle (bijective: 7168 % 8 == 0)
  const int flat = blockIdx.x + 28 * (blockIdx.y + 32 * blockIdx.z);
  const int w = (flat & 7) * 896 + (flat >> 3);
  const int bx = w % 28, by = (w / 28) & 31, e = w / 896;
  const int cn = cnt[e];
  const int m0 = by * 128;
  if (m0 >= cn) return;
  int padoff = 0;
  for (int i = 0; i < e; ++i) padoff += (cnt[i] + 127) & ~127;
  const int n0 = bx * 128;
  __shared__ unsigned short As[3][4096], Bg[3][4096], Bu[3][4096];
  const int tid = threadIdx.x, wid = tid >> 6, lane = tid & 63;
  const int wm = (wid >> 2) * 64, wn = (wid & 3) * 32;
  const int fr = lane & 15, fg = lane >> 4;
  const int srow = tid >> 2;                               // 0..127
  const int scol = (((tid & 3) ^ ((tid >> 3) & 3))) * 8;   // swizzled source chunk
  const int lr = m0 + srow;
  const int tkr = (lr < cn) ? tok[e * 4096 + lr] : 0;
  const unsigned short* ga = H2 + (long)tkr * 1024 + scol;
  const unsigned short* gb = WG + (long)e * 3584 * 1024 + (long)(n0 + srow) * 1024 + scol;
  const unsigned short* gu = WU + (long)e * 3584 * 1024 + (long)(n0 + srow) * 1024 + scol;
#define GU_STAGE(s, b)                                                         \
  do {                                                                         \
    const int ko = (s) * 32;                                                   \
    GL16(ga + ko, (char*)As[b] + wid * 1024);                                  \
    GL16(gb + ko, (char*)Bg[b] + wid * 1024);                                  \
    GL16(gu + ko, (char*)Bu[b] + wid * 1024);                                  \
  } while (0)
  f32x4 ag[4][2] = {}, au[4][2] = {};
  GU_STAGE(0, 0);
  GU_STAGE(1, 1);
  PIPE_SYNC(3);
  for (int t = 0; t < 32; ++t) {
    const int cb = t % 3;
    if (t + 2 < 32) GU_STAGE(t + 2, (t + 2) % 3);
    const unsigned short* As_ = As[cb];
    const unsigned short* Bg_ = Bg[cb];
    const unsigned short* Bu_ = Bu[cb];
    bf16x8 af[4], bgf[2], buf_[2];
#pragma unroll
    for (int i = 0; i < 4; ++i) af[i] = *(const bf16x8*)&As_[sw32(wm + i * 16 + fr, fg)];
#pragma unroll
    for (int j = 0; j < 2; ++j) {
      const int oB = sw32(wn + j * 16 + fr, fg);
      bgf[j] = *(const bf16x8*)&Bg_[oB];
      buf_[j] = *(const bf16x8*)&Bu_[oB];
    }
    SETPRIO(1);
#pragma unroll
    for (int i = 0; i < 4; ++i)
#pragma unroll
      for (int j = 0; j < 2; ++j) {
        ag[i][j] = MFMA16(af[i], bgf[j], ag[i][j]);
        au[i][j] = MFMA16(af[i], buf_[j], au[i][j]);
      }
    SETPRIO(0);
    if (t + 2 < 32) PIPE_SYNC(3);
    else if (t + 1 < 32) PIPE_SYNC(0);
  }
#undef GU_STAGE
  const int cr = fg * 4;
#pragma unroll
  for (int i = 0; i < 4; ++i)
#pragma unroll
    for (int j = 0; j < 2; ++j)
#pragma unroll
      for (int rr = 0; rr < 4; ++rr) {
        const int row = wm + i * 16 + cr + rr;  // tile-local
        const int col = n0 + wn + j * 16 + fr;
        const float gv = ag[i][j][rr];
        const float sg = gv / (1.f + __expf(-gv));  // silu
        act[(long)(padoff + m0 + row) * 3584 + col] = f2bf(sg * au[i][j][rr]);
      }
}

// MoE down GEMM + scatter: out[tok] += w * (act @ Wd^T)
// R6-exact: 512 threads (8 waves, 2Mx4N), wave 64x32, 3-stage vmcnt(2),
// XCD chunk swizzle (nwg=2048, 256/XCD = 1 expert). Twice-verified best.
__global__ __launch_bounds__(512, 4) void down_kernel(const unsigned short* __restrict__ act,
                                                      const unsigned short* __restrict__ WD,
                                                      const int* __restrict__ tok,
                                                      const float* __restrict__ wgt,
                                                      const int* __restrict__ cnt,
                                                      float* __restrict__ out) {
  const int flat = blockIdx.x + 8 * (blockIdx.y + 32 * blockIdx.z);
  const int w = (flat & 7) * 256 + (flat >> 3);
  const int bx = w & 7, by = (w >> 3) & 31, e = w >> 8;
  const int cn = cnt[e];
  const int m0 = by * 128;
  if (m0 >= cn) return;
  int padoff = 0;
  for (int i = 0; i < e; ++i) padoff += (cnt[i] + 127) & ~127;
  const int n0 = bx * 128;
  __shared__ unsigned short As[3][4096], Bs[3][4096];
  const int tid = threadIdx.x, wid = tid >> 6, lane = tid & 63;
  const int wm = (wid >> 2) * 64, wn = (wid & 3) * 32;
  const int fr = lane & 15, fg = lane >> 4;
  const int srow = tid >> 2;                               // 0..127
  const int scol = (((tid & 3) ^ ((tid >> 3) & 3))) * 8;   // swizzled source chunk
  const unsigned short* ga = act + (long)(padoff + m0 + srow) * 3584 + scol;
  const unsigned short* gb = WD + (long)e * 1024 * 3584 + (long)(n0 + srow) * 3584 + scol;
#define DN_STAGE(s, b)                                                         \
  do {                                                                         \
    const int ko = (s) * 32;                                                   \
    GL16(ga + ko, (char*)As[b] + wid * 1024);                                  \
    GL16(gb + ko, (char*)Bs[b] + wid * 1024);                                  \
  } while (0)
  f32x4 acc[4][2] = {};
  DN_STAGE(0, 0);
  DN_STAGE(1, 1);
  PIPE_SYNC(2);
  for (int t = 0; t < 112; ++t) {
    const int cb = t % 3;
    if (t + 2 < 112) DN_STAGE(t + 2, (t + 2) % 3);
    const unsigned short* As_ = As[cb];
    const unsigned short* Bs_ = Bs[cb];
    bf16x8 af[4], bf_[2];
#pragma unroll
    for (int i = 0; i < 4; ++i) af[i] = *(const bf16x8*)&As_[sw32(wm + i * 16 + fr, fg)];
#pragma unroll
    for (int j = 0; j < 2; ++j) bf_[j] = *(const bf16x8*)&Bs_[sw32(wn + j * 16 + fr, fg)];
    SETPRIO(1);
#pragma unroll
    for (int i = 0; i < 4; ++i)
#pragma unroll
      for (int j = 0; j < 2; ++j)
        acc[i][j] = MFMA16(af[i], bf_[j], acc[i][j]);
    SETPRIO(0);
    if (t + 2 < 112) PIPE_SYNC(2);
    else if (t + 1 < 112) PIPE_SYNC(0);
  }
#undef DN_STAGE
  const int cr = fg * 4;
#pragma unroll
  for (int i = 0; i < 4; ++i)
#pragma unroll
    for (int rr = 0; rr < 4; ++rr) {
      const int lrow = m0 + wm + i * 16 + cr + rr;
      if (lrow < cn) {
        const int tk = tok[e * 4096 + lrow];
        const float wv_ = wgt[e * 4096 + lrow];
#pragma unroll
        for (int j = 0; j < 2; ++j)
          atomicAdd(&out[(long)tk * 1024 + n0 + wn + j * 16 + fr], wv_ * acc[i][j][rr]);
      }
    }
}

// ---------------------------------------------------------------------------
extern "C" void kernel_launch(void* const* d_in, const int* in_sizes, int n_in,
                              void* d_out, int out_size, void* d_ws, size_t ws_size,
                              hipStream_t stream) {
  (void)in_sizes; (void)n_in; (void)out_size;
  if (ws_size < WS_NEED) {
    fprintf(stderr, "kernel_launch: ws too small: %zu < %zu\n", ws_size, (size_t)WS_NEED);
  }
  const float* x    = (const float*)d_in[0];
  const float* n1s  = (const float*)d_in[1];
  const float* n2s  = (const float*)d_in[2];
  const float* wq   = (const float*)d_in[3];
  const float* wk   = (const float*)d_in[4];
  const float* wv   = (const float*)d_in[5];
  const float* wo   = (const float*)d_in[6];
  const float* wrt  = (const float*)d_in[7];
  const float* wg   = (const float*)d_in[8];
  const float* wu   = (const float*)d_in[9];
  const float* wd   = (const float*)d_in[10];
  float* out = (float*)d_out;
  char* W = (char*)d_ws;

  unsigned short* WQH = (unsigned short*)(W + O_WQKVT_HI);
  unsigned short* WQL = (unsigned short*)(W + O_WQKVT_LO);
  unsigned short* WOH = (unsigned short*)(W + O_WOT_HI);
  unsigned short* WOL = (unsigned short*)(W + O_WOT_LO);
  unsigned short* WGT = (unsigned short*)(W + O_WGT);
  unsigned short* WUT = (unsigned short*)(W + O_WUT);
  unsigned short* WDT = (unsigned short*)(W + O_WDT);
  unsigned short* H2  = (unsigned short*)(W + O_H2);
  int* TOK    = (int*)(W + O_TOK);
  float* WGTL = (float*)(W + O_WGTL);
  int* CNT    = (int*)(W + O_CNT);
  unsigned short* HSH = (unsigned short*)(W + O_HSHI);
  unsigned short* HSL = (unsigned short*)(W + O_HSLO);
  float* QKV = (float*)(W + O_QKV);
  unsigned short* QHI = (unsigned short*)(W + O_QHI);
  unsigned short* QLO = (unsigned short*)(W + O_QLO);
  unsigned short* KHI = (unsigned short*)(W + O_KHI);
  unsigned short* KLO = (unsigned short*)(W + O_KLO);
  unsigned short* VTH = (unsigned short*)(W + O_VTH);
  unsigned short* VTL = (unsigned short*)(W + O_VTL);
  unsigned short* AHI = (unsigned short*)(W + O_AHI);
  unsigned short* ALO = (unsigned short*)(W + O_ALO);
  float* XATTN = (float*)(W + O_XATTN);
  unsigned short* ACT = (unsigned short*)(W + O_ACT);

  zero_cnt_kernel<<<1, 64, 0, stream>>>(CNT);
  // RMSNorm1 -> split hs
  rmsnorm_kernel<<<4096, 256, 0, stream>>>(x, n1s, HSH, HSL);
  // weight transposes (per call; bf16 [N][K] layouts)
  transpose_cvt_split<<<dim3(16, 16, 1), 256, 0, stream>>>(wq, WQH, WQL, 1024, 1024);
  transpose_cvt_split<<<dim3(4, 16, 1), 256, 0, stream>>>(wk, WQH + 1024L * 1024, WQL + 1024L * 1024, 1024, 256);
  transpose_cvt_split<<<dim3(4, 16, 1), 256, 0, stream>>>(wv, WQH + 1280L * 1024, WQL + 1280L * 1024, 1024, 256);
  transpose_cvt_split<<<dim3(16, 16, 1), 256, 0, stream>>>(wo, WOH, WOL, 1024, 1024);
  transpose_cvt<<<dim3(56, 16, 8), 256, 0, stream>>>(wg, WGT, 1024, 3584, 1024L * 3584, 3584L * 1024);
  transpose_cvt<<<dim3(56, 16, 8), 256, 0, stream>>>(wu, WUT, 1024, 3584, 1024L * 3584, 3584L * 1024);
  transpose_cvt<<<dim3(16, 56, 8), 256, 0, stream>>>(wd, WDT, 3584, 1024, 3584L * 1024, 1024L * 3584);
  // QKV projection (split GEMM, f32 out)
  gemm_split<<<dim3(12, 32, 1), 256, 0, stream>>>(HSH, HSL, WQH, WQL, nullptr, QKV, 4096, 1536, 1024);
  // RoPE + split; V transpose + split
  rope_kernel<<<4096, 256, 0, stream>>>(QKV, QHI, QLO, KHI, KLO);
  vt_split_kernel<<<dim3(32, 4, 2), 256, 0, stream>>>(QKV, VTH, VTL);
  // attention
  attn_kernel<<<dim3(32, 16, 2), 256, 0, stream>>>(QHI, QLO, KHI, KLO, VTH, VTL, AHI, ALO);
  // out projection + residual
  gemm_split<<<dim3(8, 32, 1), 256, 0, stream>>>(AHI, ALO, WOH, WOL, x, XATTN, 4096, 1024, 1024);
  // fused: residual init + RMSNorm2 -> H2 + router -> logits/lists
  router_fused_kernel<<<4096, 256, 0, stream>>>(XATTN, n2s, wrt, out + 4194304, H2, out,
                                                TOK, WGTL, CNT);
  gateup_kernel<<<dim3(28, 32, 8), 512, 0, stream>>>(H2, WGT, WUT, TOK, CNT, ACT);
  down_kernel<<<dim3(8, 32, 8), 512, 0, stream>>>(ACT, WDT, TOK, WGTL, CNT, out);
}

// Round 10
// 678.381 us; speedup vs baseline: 1.0526x; 1.0022x over previous
//
#include <hip/hip_runtime.h>
#include <hip/hip_bf16.h>
#include <cstdio>

// ---------------------------------------------------------------------------
// MixtralTransformerDecoder: B=2 S=2048 H=1024 NQ=16 NKV=4 HD=64 I=3584 E=8
// TOP_K=2, sliding window 512.
// Split-bf16 (hi+lo) MFMA upstream of the router; plain bf16 MFMA for experts.
// R10: RoPE cos/sin precomputed into a [2048][32] float2 table (bit-identical
// math, removes 2.6M double-exp2+sincosf from the hot kernel); table lives in
// the dead-at-that-point AHI region. zero_cnt folded into the table kernel.
// All else identical to R9 (best: 680 us).
// ---------------------------------------------------------------------------

typedef __bf16 bf16x8 __attribute__((ext_vector_type(8)));
typedef float f32x4 __attribute__((ext_vector_type(4)));

#define MFMA16(a, b, c) __builtin_amdgcn_mfma_f32_16x16x32_bf16((a), (b), (c), 0, 0, 0)
#define GL16(g, l)                                                             \
  __builtin_amdgcn_global_load_lds(                                            \
      (const __attribute__((address_space(1))) void*)(g),                      \
      (__attribute__((address_space(3))) void*)(l), 16, 0, 0)
#define WAIT_VM0() asm volatile("s_waitcnt vmcnt(0)" ::: "memory")
#define SETPRIO(n) __builtin_amdgcn_s_setprio(n)
// counted-vmcnt + raw barrier + compiler fence (T4; __syncthreads would drain)
#define PIPE_SYNC(n)                                                           \
  do {                                                                         \
    asm volatile("s_waitcnt vmcnt(" #n ")" ::: "memory");                      \
    __builtin_amdgcn_s_barrier();                                              \
    asm volatile("" ::: "memory");                                             \
  } while (0)

__device__ __forceinline__ unsigned short f2bf(float f) {
  unsigned u = __builtin_bit_cast(unsigned, f);
  u += 0x7fffu + ((u >> 16) & 1u);
  return (unsigned short)(u >> 16);
}
__device__ __forceinline__ float bf2f(unsigned short h) {
  unsigned u = ((unsigned)h) << 16;
  return __builtin_bit_cast(float, u);
}
// swizzled element offset for [row][32 bf16] LDS tiles (64B rows, 4 chunks)
__device__ __forceinline__ int sw32(int row, int chunk) {
  return row * 32 + ((chunk ^ ((row >> 1) & 3)) * 8);
}

// ---------------------------------------------------------------------------
// Workspace layout (bytes)
// ---------------------------------------------------------------------------
static constexpr size_t O_WQKVT_HI = 0;                           // [1536][1024] bf16
static constexpr size_t SZ_WQKVT   = 1536UL * 1024 * 2;
static constexpr size_t O_WQKVT_LO = O_WQKVT_HI + SZ_WQKVT;
static constexpr size_t O_WOT_HI   = O_WQKVT_LO + SZ_WQKVT;       // [1024][1024] bf16
static constexpr size_t SZ_WOT     = 1024UL * 1024 * 2;
static constexpr size_t O_WOT_LO   = O_WOT_HI + SZ_WOT;
static constexpr size_t O_WGT      = O_WOT_LO + SZ_WOT;           // [8][3584][1024] bf16
static constexpr size_t SZ_WE      = 8UL * 3584 * 1024 * 2;
static constexpr size_t O_WUT      = O_WGT + SZ_WE;
static constexpr size_t O_WDT      = O_WUT + SZ_WE;               // [8][1024][3584] bf16
static constexpr size_t O_H2       = O_WDT + SZ_WE;               // [4096][1024] bf16
static constexpr size_t SZ_BF_TH   = 4096UL * 1024 * 2;
static constexpr size_t O_TOK      = O_H2 + SZ_BF_TH;             // [8][4096] i32
static constexpr size_t O_WGTL     = O_TOK + 8UL * 4096 * 4;      // [8][4096] f32
static constexpr size_t O_CNT      = O_WGTL + 8UL * 4096 * 4;     // [8] i32
static constexpr size_t O_DYN      = O_CNT + 256;
// DYN region (dead before MoE; ACT aliases its head)
static constexpr size_t O_HSHI  = O_DYN;
static constexpr size_t O_HSLO  = O_HSHI + SZ_BF_TH;
static constexpr size_t O_QKV   = O_HSLO + SZ_BF_TH;              // [4096][1536] f32
static constexpr size_t O_QHI   = O_QKV + 4096UL * 1536 * 4;      // [2][16][2048][64] bf16
static constexpr size_t O_QLO   = O_QHI + SZ_BF_TH;
static constexpr size_t O_KHI   = O_QLO + SZ_BF_TH;               // [2][4][2048][64] bf16
static constexpr size_t SZ_BF_T256 = 4096UL * 256 * 2;
static constexpr size_t O_KLO   = O_KHI + SZ_BF_T256;
static constexpr size_t O_VTH   = O_KLO + SZ_BF_T256;             // [2][4][64][2048] bf16
static constexpr size_t O_VTL   = O_VTH + SZ_BF_T256;
static constexpr size_t O_AHI   = O_VTL + SZ_BF_T256;             // [4096][1024] bf16
static constexpr size_t O_ALO   = O_AHI + SZ_BF_TH;
static constexpr size_t O_XATTN = O_ALO + SZ_BF_TH;               // [4096][1024] f32
static constexpr size_t O_END   = O_XATTN + 4096UL * 1024 * 4;
static constexpr size_t O_ACT   = O_DYN;   // [<=9208][3584] bf16 alias (66MB, before XATTN)
// RoPE table [2048][32] float2 = 512KB: aliases O_AHI (dead until attn_kernel
// writes AHI, which happens after rope_kernel has consumed the table).
static constexpr size_t O_ROPET = O_AHI;
static constexpr size_t WS_NEED = O_END;

// ---------------------------------------------------------------------------
// small kernels
// ---------------------------------------------------------------------------
// RoPE cos/sin table: tbl[s][p] = (cos(s*inv_p), sin(s*inv_p)), bit-identical
// expressions to the old in-kernel computation. Also zeroes the expert counts.
__global__ __launch_bounds__(256) void rope_table_kernel(float2* __restrict__ tbl,
                                                         int* __restrict__ cnt) {
  const int i = blockIdx.x * 256 + threadIdx.x;  // 65536 = 2048 s x 32 p
  const int s = i >> 5, p = i & 31;
  const float inv = (float)exp2(-(double)p * 0.4152410118609203);  // 10000^(-p/32)
  float sn, cs;
  sincosf((float)s * inv, &sn, &cs);
  tbl[i] = make_float2(cs, sn);
  if (i < 8) cnt[i] = 0;
}

// RMSNorm: x[4096][1024] f32 -> hi (+ optional lo) bf16
__global__ __launch_bounds__(256) void rmsnorm_kernel(const float* __restrict__ x,
                                                      const float* __restrict__ scale,
                                                      unsigned short* __restrict__ hi,
                                                      unsigned short* __restrict__ lo) {
  const int t = blockIdx.x, tid = threadIdx.x;
  const float4 v = *(const float4*)&x[(long)t * 1024 + tid * 4];
  float ss = v.x * v.x + v.y * v.y + v.z * v.z + v.w * v.w;
#pragma unroll
  for (int off = 32; off >= 1; off >>= 1) ss += __shfl_down(ss, off);
  __shared__ float red[4];
  if ((tid & 63) == 0) red[tid >> 6] = ss;
  __syncthreads();
  const float r = rsqrtf((red[0] + red[1] + red[2] + red[3]) * (1.0f / 1024.0f) + 1e-5f);
  const float4 sc = *(const float4*)&scale[tid * 4];
  float o[4] = {v.x * r * sc.x, v.y * r * sc.y, v.z * r * sc.z, v.w * r * sc.w};
  ushort4 hh, ll;
  unsigned short* hp = (unsigned short*)&hh;
  unsigned short* lp = (unsigned short*)&ll;
#pragma unroll
  for (int i = 0; i < 4; ++i) {
    hp[i] = f2bf(o[i]);
    lp[i] = f2bf(o[i] - bf2f(hp[i]));
  }
  *(ushort4*)&hi[(long)t * 1024 + tid * 4] = hh;
  if (lo) *(ushort4*)&lo[(long)t * 1024 + tid * 4] = ll;
}

// transpose+convert: src f32 [R][C] -> dst bf16 [C][R]
__global__ __launch_bounds__(256) void transpose_cvt(const float* __restrict__ src,
                                                     unsigned short* __restrict__ dst,
                                                     int R, int C, long zsrc, long zdst) {
  src += (long)blockIdx.z * zsrc;
  dst += (long)blockIdx.z * zdst;
  const int c0 = blockIdx.x * 64, r0 = blockIdx.y * 64, tid = threadIdx.x;
  __shared__ float tb[64][65];
#pragma unroll
  for (int p = 0; p < 4; ++p) {
    const int r = p * 16 + (tid >> 4), c = (tid & 15) * 4;
    const float4 v = *(const float4*)&src[(long)(r0 + r) * C + c0 + c];
    tb[c + 0][r] = v.x; tb[c + 1][r] = v.y; tb[c + 2][r] = v.z; tb[c + 3][r] = v.w;
  }
  __syncthreads();
  const int dr = tid >> 2, s0 = (tid & 3) * 16;
  __align__(16) unsigned short tmp[16];
#pragma unroll
  for (int i = 0; i < 16; ++i) tmp[i] = f2bf(tb[dr][s0 + i]);
  const long o = (long)(c0 + dr) * R + r0 + s0;
  *(uint4*)&dst[o] = *(const uint4*)&tmp[0];
  *(uint4*)&dst[o + 8] = *(const uint4*)&tmp[8];
}

// transpose+convert+split: src f32 [R][C] -> hi,lo bf16 [C][R]
__global__ __launch_bounds__(256) void transpose_cvt_split(const float* __restrict__ src,
                                                           unsigned short* __restrict__ dh,
                                                           unsigned short* __restrict__ dl,
                                                           int R, int C) {
  const int c0 = blockIdx.x * 64, r0 = blockIdx.y * 64, tid = threadIdx.x;
  __shared__ float tb[64][65];
#pragma unroll
  for (int p = 0; p < 4; ++p) {
    const int r = p * 16 + (tid >> 4), c = (tid & 15) * 4;
    const float4 v = *(const float4*)&src[(long)(r0 + r) * C + c0 + c];
    tb[c + 0][r] = v.x; tb[c + 1][r] = v.y; tb[c + 2][r] = v.z; tb[c + 3][r] = v.w;
  }
  __syncthreads();
  const int dr = tid >> 2, s0 = (tid & 3) * 16;
  __align__(16) unsigned short th[16], tl[16];
#pragma unroll
  for (int i = 0; i < 16; ++i) {
    const float f = tb[dr][s0 + i];
    th[i] = f2bf(f);
    tl[i] = f2bf(f - bf2f(th[i]));
  }
  const long o = (long)(c0 + dr) * R + r0 + s0;
  *(uint4*)&dh[o] = *(const uint4*)&th[0];
  *(uint4*)&dh[o + 8] = *(const uint4*)&th[8];
  *(uint4*)&dl[o] = *(const uint4*)&tl[0];
  *(uint4*)&dl[o + 8] = *(const uint4*)&tl[8];
}

// ---------------------------------------------------------------------------
// split-bf16 GEMM: C[M][N] = (Ahi+Alo)[M][K] @ (Bhi+Blo)[N][K]^T (+resid)
// 128x128 tile, BK=32, dbuf prefetch + swizzle + setprio (R6 form).
// ---------------------------------------------------------------------------
__global__ __launch_bounds__(256) void gemm_split(const unsigned short* __restrict__ Ahi,
                                                  const unsigned short* __restrict__ Alo,
                                                  const unsigned short* __restrict__ Bhi,
                                                  const unsigned short* __restrict__ Blo,
                                                  const float* __restrict__ resid,
                                                  float* __restrict__ C,
                                                  int M, int N, int K) {
  __shared__ unsigned short Ash[2][4096], Asl[2][4096], Bsh[2][4096], Bsl[2][4096];
  const int tid = threadIdx.x, wid = tid >> 6, lane = tid & 63;
  const int m0 = blockIdx.y * 128, n0 = blockIdx.x * 128;
  const int wm = (wid >> 1) * 64, wn = (wid & 1) * 64;
  const int fr = lane & 15, fg = lane >> 4;
  const int srow = tid >> 2;
  const int scol = (((tid & 3) ^ ((tid >> 3) & 3))) * 8;  // swizzled source chunk
  const long aoff = (long)(m0 + srow) * K + scol;
  const long boff = (long)(n0 + srow) * K + scol;
  const long h64 = 64L * K;
  char* a0 = (char*)Ash[0] + wid * 1024; char* a1 = (char*)Ash[1] + wid * 1024;
  char* al0 = (char*)Asl[0] + wid * 1024; char* al1 = (char*)Asl[1] + wid * 1024;
  char* b0 = (char*)Bsh[0] + wid * 1024; char* b1 = (char*)Bsh[1] + wid * 1024;
  char* bl0 = (char*)Bsl[0] + wid * 1024; char* bl1 = (char*)Bsl[1] + wid * 1024;
#define GS_STAGE(koff, pah_, pal_, pbh_, pbl_)                                 \
  do {                                                                         \
    GL16(Ahi + aoff + (koff), (pah_));                                         \
    GL16(Ahi + aoff + h64 + (koff), (pah_) + 4096);                            \
    GL16(Alo + aoff + (koff), (pal_));                                         \
    GL16(Alo + aoff + h64 + (koff), (pal_) + 4096);                            \
    GL16(Bhi + boff + (koff), (pbh_));                                         \
    GL16(Bhi + boff + h64 + (koff), (pbh_) + 4096);                            \
    GL16(Blo + boff + (koff), (pbl_));                                         \
    GL16(Blo + boff + h64 + (koff), (pbl_) + 4096);                            \
  } while (0)
  f32x4 acc[4][4] = {};
  GS_STAGE(0, a0, al0, b0, bl0);
  WAIT_VM0();
  __syncthreads();
  int cur = 0;
  for (int k0 = 0; k0 < K; k0 += 32) {
    const int kn = k0 + 32;
    if (kn < K) {
      if (cur) GS_STAGE(kn, a0, al0, b0, bl0);
      else     GS_STAGE(kn, a1, al1, b1, bl1);
    }
    const unsigned short* As_ = Ash[cur];
    const unsigned short* Al_ = Asl[cur];
    const unsigned short* Bs_ = Bsh[cur];
    const unsigned short* Bl_ = Bsl[cur];
    bf16x8 ah[4], al[4], bh[4], bl[4];
#pragma unroll
    for (int i = 0; i < 4; ++i) {
      const int oA = sw32(wm + i * 16 + fr, fg);
      const int oB = sw32(wn + i * 16 + fr, fg);
      ah[i] = *(const bf16x8*)&As_[oA];
      al[i] = *(const bf16x8*)&Al_[oA];
      bh[i] = *(const bf16x8*)&Bs_[oB];
      bl[i] = *(const bf16x8*)&Bl_[oB];
    }
    SETPRIO(1);
#pragma unroll
    for (int i = 0; i < 4; ++i)
#pragma unroll
      for (int j = 0; j < 4; ++j) {
        acc[i][j] = MFMA16(al[i], bh[j], acc[i][j]);
        acc[i][j] = MFMA16(ah[i], bl[j], acc[i][j]);
        acc[i][j] = MFMA16(ah[i], bh[j], acc[i][j]);
      }
    SETPRIO(0);
    WAIT_VM0();
    __syncthreads();
    cur ^= 1;
  }
#undef GS_STAGE
  const int cr = fg * 4;
#pragma unroll
  for (int i = 0; i < 4; ++i)
#pragma unroll
    for (int j = 0; j < 4; ++j)
#pragma unroll
      for (int rr = 0; rr < 4; ++rr) {
        const int row = m0 + wm + i * 16 + cr + rr;
        const int col = n0 + wn + j * 16 + fr;
        float v = acc[i][j][rr];
        if (resid) v += resid[(long)row * N + col];
        C[(long)row * N + col] = v;
      }
}

// ---------------------------------------------------------------------------
// RoPE + split: qkv f32 [4096][1536] -> Qhi/Qlo (scaled 1/8), Khi/Klo
// R10: cos/sin from precomputed table (bit-identical values).
// ---------------------------------------------------------------------------
__global__ __launch_bounds__(256) void rope_kernel(const float* __restrict__ qkv,
                                                   const float2* __restrict__ tbl,
                                                   unsigned short* __restrict__ Qh,
                                                   unsigned short* __restrict__ Ql,
                                                   unsigned short* __restrict__ Kh,
                                                   unsigned short* __restrict__ Kl) {
  const int t = blockIdx.x, b = t >> 11, s = t & 2047;
  const float* src = qkv + (long)t * 1536;
  const float2* trow = tbl + (s << 5);
  for (int task = threadIdx.x; task < 640; task += 256) {
    const int head = task >> 5, p = task & 31;
    const float* hp = src + head * 64;
    const float2 t2 = trow[p];
    const float cs = t2.x, sn = t2.y;
    const float x0 = hp[2 * p], x1 = hp[2 * p + 1], xa = hp[p], xb = hp[32 + p];
    float o0 = x0 * cs - xb * sn;
    float o1 = x1 * cs + xa * sn;
    unsigned short *dh, *dl;
    long base;
    if (head < 16) {
      o0 *= 0.125f; o1 *= 0.125f;  // fold 1/sqrt(64) into Q
      base = ((long)(b * 16 + head) * 2048 + s) * 64;
      dh = Qh; dl = Ql;
    } else {
      base = ((long)(b * 4 + (head - 16)) * 2048 + s) * 64;
      dh = Kh; dl = Kl;
    }
    unsigned short h0 = f2bf(o0);
    dh[base + 2 * p] = h0; dl[base + 2 * p] = f2bf(o0 - bf2f(h0));
    unsigned short h1 = f2bf(o1);
    dh[base + 2 * p + 1] = h1; dl[base + 2 * p + 1] = f2bf(o1 - bf2f(h1));
  }
}

// V transpose+split: -> Vth/Vtl [2][4][64][2048] bf16
__global__ __launch_bounds__(256) void vt_split_kernel(const float* __restrict__ qkv,
                                                       unsigned short* __restrict__ Vh,
                                                       unsigned short* __restrict__ Vl) {
  const int st = blockIdx.x * 64, g = blockIdx.y, b = blockIdx.z, tid = threadIdx.x;
  __shared__ float tb[64][65];
  const float* src = qkv + (long)(b * 2048 + st) * 1536 + 1280 + g * 64;
#pragma unroll
  for (int p = 0; p < 4; ++p) {
    const int r = p * 16 + (tid >> 4), c = (tid & 15) * 4;
    const float4 v = *(const float4*)&src[(long)r * 1536 + c];
    tb[c + 0][r] = v.x; tb[c + 1][r] = v.y; tb[c + 2][r] = v.z; tb[c + 3][r] = v.w;
  }
  __syncthreads();
  const int dr = tid >> 2, s0 = (tid & 3) * 16;
  __align__(16) unsigned short hh[16], ll[16];
#pragma unroll
  for (int i = 0; i < 16; ++i) {
    const float f = tb[dr][s0 + i];
    hh[i] = f2bf(f);
    ll[i] = f2bf(f - bf2f(hh[i]));
  }
  const long dst = ((long)(b * 4 + g) * 64 + dr) * 2048 + st + s0;
  *(uint4*)&Vh[dst] = *(const uint4*)&hh[0];
  *(uint4*)&Vh[dst + 8] = *(const uint4*)&hh[8];
  *(uint4*)&Vl[dst] = *(const uint4*)&ll[0];
  *(uint4*)&Vl[dst + 8] = *(const uint4*)&ll[8];
}

// ---------------------------------------------------------------------------
// Flash attention, split-bf16 MFMA, sliding window 512, causal (R6 form).
// ---------------------------------------------------------------------------
__global__ __launch_bounds__(256) void attn_kernel(const unsigned short* __restrict__ Qh,
                                                   const unsigned short* __restrict__ Ql,
                                                   const unsigned short* __restrict__ Kh,
                                                   const unsigned short* __restrict__ Kl,
                                                   const unsigned short* __restrict__ Vh,
                                                   const unsigned short* __restrict__ Vl,
                                                   unsigned short* __restrict__ Ohi,
                                                   unsigned short* __restrict__ Olo) {
  const int qt = blockIdx.x, h = blockIdx.y, b = blockIdx.z, g = h >> 2;
  const int q0 = qt * 64, tid = threadIdx.x, wid = tid >> 6, lane = tid & 63;
  const int fr = lane & 15, fg = lane >> 4;
  __shared__ unsigned short Ksh[2][2048], Ksl[2][2048];  // [32 keys][64 d]
  __shared__ unsigned short Vsh[2][2048], Vsl[2][2048];  // [64 d][32 keys]
  __shared__ unsigned short Ph[4][512], Pl[4][512];      // per-wave [16][32]

  const long qoff = ((long)(b * 16 + h) * 2048 + q0 + wid * 16 + fr) * 64;
  bf16x8 qh[2], ql[2];
  qh[0] = *(const bf16x8*)&Qh[qoff + fg * 8];
  qh[1] = *(const bf16x8*)&Qh[qoff + 32 + fg * 8];
  ql[0] = *(const bf16x8*)&Ql[qoff + fg * 8];
  ql[1] = *(const bf16x8*)&Ql[qoff + 32 + fg * 8];

  f32x4 o[4] = {};
  float mrow[4], lrow[4];
#pragma unroll
  for (int rr = 0; rr < 4; ++rr) { mrow[rr] = -1e30f; lrow[rr] = 0.f; }

  const int jmin = (q0 >= 511) ? (q0 - 511) : 0;
  const int jt0 = jmin & ~31;
  const long kbase = ((long)(b * 4 + g) * 2048) * 64;
  const long vbase = ((long)(b * 4 + g) * 64) * 2048;
  const int srK = tid >> 3;                                  // 0..31
  const int scK = (((tid & 7) ^ (srK & 7))) * 8;             // swizzled K source chunk
  const int srV = tid >> 2;                                  // 0..63
  const int scV = (((tid & 3) ^ ((srV >> 1) & 3))) * 8;      // swizzled V source chunk
  char* kh0 = (char*)Ksh[0] + wid * 1024; char* kh1 = (char*)Ksh[1] + wid * 1024;
  char* kl0 = (char*)Ksl[0] + wid * 1024; char* kl1 = (char*)Ksl[1] + wid * 1024;
  char* vh0 = (char*)Vsh[0] + wid * 1024; char* vh1 = (char*)Vsh[1] + wid * 1024;
  char* vl0 = (char*)Vsl[0] + wid * 1024; char* vl1 = (char*)Vsl[1] + wid * 1024;
#define ATTN_STAGE(jt_, kh_, kl_, vh_, vl_)                                    \
  do {                                                                         \
    const long ko = kbase + (long)((jt_) + srK) * 64 + scK;                    \
    GL16(Kh + ko, (kh_));                                                      \
    GL16(Kl + ko, (kl_));                                                      \
    const long vo = vbase + (long)srV * 2048 + (jt_) + scV;                    \
    GL16(Vh + vo, (vh_));                                                      \
    GL16(Vl + vo, (vl_));                                                      \
  } while (0)

  ATTN_STAGE(jt0, kh0, kl0, vh0, vl0);
  WAIT_VM0();
  __syncthreads();
  int cur = 0;
  for (int jt = jt0; jt < q0 + 64; jt += 32) {
    const int jn = jt + 32;
    if (jn < q0 + 64) {
      if (cur) ATTN_STAGE(jn, kh0, kl0, vh0, vl0);
      else     ATTN_STAGE(jn, kh1, kl1, vh1, vl1);
    }
    const unsigned short* KH = Ksh[cur];
    const unsigned short* KL = Ksl[cur];
    const unsigned short* VH = Vsh[cur];
    const unsigned short* VL = Vsl[cur];

    // ---- QK^T (3-term split); K rows 128B -> chunk ^= row&7 ----
    f32x4 sf[2] = {};
#pragma unroll
    for (int cf = 0; cf < 2; ++cf)
#pragma unroll
      for (int dc = 0; dc < 2; ++dc) {
        const int row = cf * 16 + fr;
        const int off = row * 64 + (((dc * 4 + fg) ^ (row & 7)) * 8);
        const bf16x8 kh = *(const bf16x8*)&KH[off];
        const bf16x8 kl = *(const bf16x8*)&KL[off];
        sf[cf] = MFMA16(ql[dc], kh, sf[cf]);
        sf[cf] = MFMA16(qh[dc], kl, sf[cf]);
        sf[cf] = MFMA16(qh[dc], kh, sf[cf]);
      }

    // ---- mask + online softmax ----
    float sv[2][4];
#pragma unroll
    for (int cf = 0; cf < 2; ++cf) {
      const int j = jt + cf * 16 + fr;
#pragma unroll
      for (int rr = 0; rr < 4; ++rr) {
        const int q = q0 + wid * 16 + fg * 4 + rr;
        const bool ok = (j <= q) && (j >= q - 511);
        sv[cf][rr] = ok ? sf[cf][rr] : -1e30f;
      }
    }
    float scl_[4];
#pragma unroll
    for (int rr = 0; rr < 4; ++rr) {
      float mx = fmaxf(sv[0][rr], sv[1][rr]);
      mx = fmaxf(mx, __shfl_xor(mx, 1));
      mx = fmaxf(mx, __shfl_xor(mx, 2));
      mx = fmaxf(mx, __shfl_xor(mx, 4));
      mx = fmaxf(mx, __shfl_xor(mx, 8));
      const float mn = fmaxf(mrow[rr], mx);
      scl_[rr] = __expf(mrow[rr] - mn);
      mrow[rr] = mn;
    }
    float ps[2][4], rs[4] = {0.f, 0.f, 0.f, 0.f};
#pragma unroll
    for (int cf = 0; cf < 2; ++cf)
#pragma unroll
      for (int rr = 0; rr < 4; ++rr) {
        const float p = (sv[cf][rr] > -1e29f) ? __expf(sv[cf][rr] - mrow[rr]) : 0.f;
        ps[cf][rr] = p;
        rs[rr] += p;
      }
#pragma unroll
    for (int rr = 0; rr < 4; ++rr) {
      float r = rs[rr];
      r += __shfl_xor(r, 1);
      r += __shfl_xor(r, 2);
      r += __shfl_xor(r, 4);
      r += __shfl_xor(r, 8);
      lrow[rr] = lrow[rr] * scl_[rr] + r;
      o[0][rr] *= scl_[rr]; o[1][rr] *= scl_[rr];
      o[2][rr] *= scl_[rr]; o[3][rr] *= scl_[rr];
    }
    // ---- P -> LDS (split, swizzled [16 q][32 k]) ----
#pragma unroll
    for (int cf = 0; cf < 2; ++cf)
#pragma unroll
      for (int rr = 0; rr < 4; ++rr) {
        const int q = fg * 4 + rr, k = cf * 16 + fr;
        const int idx = q * 32 + (((k >> 3) ^ ((q >> 1) & 3)) * 8) + (k & 7);
        const unsigned short hb = f2bf(ps[cf][rr]);
        Ph[wid][idx] = hb;
        Pl[wid][idx] = f2bf(ps[cf][rr] - bf2f(hb));
      }
    const int pro = sw32(fr, fg);
    const bf16x8 pah = *(const bf16x8*)&Ph[wid][pro];
    const bf16x8 pal = *(const bf16x8*)&Pl[wid][pro];
    // ---- PV (3-term split); V rows 64B -> sw32 ----
#pragma unroll
    for (int df = 0; df < 4; ++df) {
      const int vo = sw32(df * 16 + fr, fg);
      const bf16x8 vh = *(const bf16x8*)&VH[vo];
      const bf16x8 vl = *(const bf16x8*)&VL[vo];
      o[df] = MFMA16(pal, vh, o[df]);
      o[df] = MFMA16(pah, vl, o[df]);
      o[df] = MFMA16(pah, vh, o[df]);
    }
    WAIT_VM0();
    __syncthreads();
    cur ^= 1;
  }
#undef ATTN_STAGE
  // ---- epilogue: normalize, split, store ----
#pragma unroll
  for (int df = 0; df < 4; ++df)
#pragma unroll
    for (int rr = 0; rr < 4; ++rr) {
      const int q = q0 + wid * 16 + fg * 4 + rr;
      const float v = o[df][rr] / lrow[rr];
      const long oi = ((long)(b * 2048 + q)) * 1024 + h * 64 + df * 16 + fr;
      const unsigned short hb = f2bf(v);
      Ohi[oi] = hb;
      Olo[oi] = f2bf(v - bf2f(hb));
    }
}

// ---------------------------------------------------------------------------
// Fused epilogue: residual init (out = xattn), RMSNorm2 -> H2 bf16,
// router logits (f32) -> d_out tail, top-2 + compaction lists.
// ---------------------------------------------------------------------------
__global__ __launch_bounds__(256) void router_fused_kernel(const float* __restrict__ xattn,
                                                           const float* __restrict__ scale,
                                                           const float* __restrict__ wr,
                                                           float* __restrict__ logits,
                                                           unsigned short* __restrict__ h2,
                                                           float* __restrict__ outres,
                                                           int* __restrict__ tok,
                                                           float* __restrict__ wgt,
                                                           int* __restrict__ cnt) {
  const int t = blockIdx.x, tid = threadIdx.x;
  const float4 v = *(const float4*)&xattn[(long)t * 1024 + tid * 4];
  *(float4*)&outres[(long)t * 1024 + tid * 4] = v;  // residual init of decoder_output
  float ss = v.x * v.x + v.y * v.y + v.z * v.z + v.w * v.w;
#pragma unroll
  for (int off = 32; off >= 1; off >>= 1) ss += __shfl_down(ss, off);
  __shared__ float red[4];
  __shared__ float redE[4][8];
  __shared__ float lg[8];
  if ((tid & 63) == 0) red[tid >> 6] = ss;
  __syncthreads();
  const float r = rsqrtf((red[0] + red[1] + red[2] + red[3]) * (1.0f / 1024.0f) + 1e-5f);
  const float4 sc = *(const float4*)&scale[tid * 4];
  const float hv[4] = {v.x * r * sc.x, v.y * r * sc.y, v.z * r * sc.z, v.w * r * sc.w};
  // H2 row (bit-identical to the old rmsnorm_kernel hi-path)
  ushort4 hh;
  unsigned short* hp = (unsigned short*)&hh;
#pragma unroll
  for (int i = 0; i < 4; ++i) hp[i] = f2bf(hv[i]);
  *(ushort4*)&h2[(long)t * 1024 + tid * 4] = hh;
  // router logits
  float part[8];
#pragma unroll
  for (int e = 0; e < 8; ++e) part[e] = 0.f;
#pragma unroll
  for (int i = 0; i < 4; ++i) {
    const float* w = &wr[(long)(tid * 4 + i) * 8];
#pragma unroll
    for (int e = 0; e < 8; ++e) part[e] = fmaf(hv[i], w[e], part[e]);
  }
#pragma unroll
  for (int off = 32; off >= 1; off >>= 1)
#pragma unroll
    for (int e = 0; e < 8; ++e) part[e] += __shfl_down(part[e], off);
  if ((tid & 63) == 0)
#pragma unroll
    for (int e = 0; e < 8; ++e) redE[tid >> 6][e] = part[e];
  __syncthreads();
  if (tid < 8) {
    const float l8 = redE[0][tid] + redE[1][tid] + redE[2][tid] + redE[3][tid];
    lg[tid] = l8;
    logits[(long)t * 8 + tid] = l8;
  }
  __syncthreads();
  if (tid == 0) {
    float mx = lg[0];
#pragma unroll
    for (int e = 1; e < 8; ++e) mx = fmaxf(mx, lg[e]);
    float p[8];
#pragma unroll
    for (int e = 0; e < 8; ++e) p[e] = __expf(lg[e] - mx);
    int i1 = 0;
#pragma unroll
    for (int e = 1; e < 8; ++e) if (p[e] > p[i1]) i1 = e;
    int i2 = (i1 == 0) ? 1 : 0;
#pragma unroll
    for (int e = 0; e < 8; ++e) if (e != i2 && e != i1 && p[e] > p[i2]) i2 = e;
    const float wsum = p[i1] + p[i2];
    const float w1 = p[i1] / wsum, w2 = p[i2] / wsum;
    const int pos1 = atomicAdd(&cnt[i1], 1);
    tok[i1 * 4096 + pos1] = t; wgt[i1 * 4096 + pos1] = w1;
    const int pos2 = atomicAdd(&cnt[i2], 1);
    tok[i2 * 4096 + pos2] = t; wgt[i2 * 4096 + pos2] = w2;
  }
}

// ---------------------------------------------------------------------------
// MoE gate+up fused GEMM (gathered A): act = silu(h2@Wg^T) * (h2@Wu^T), bf16
// R3 structure: 512 threads (8 waves, 2Mx4N), 3-stage pipeline, vmcnt(3).
// + XCD chunk swizzle.
// ---------------------------------------------------------------------------
__global__ __launch_bounds__(512, 4) void gateup_kernel(const unsigned short* __restrict__ H2,
                                                        const unsigned short* __restrict__ WG,
                                                        const unsigned short* __restrict__ WU,
                                                        const int* __restrict__ tok,
                                                        const int* __restrict__ cnt,
                                                        unsigned short* __restrict__ act) {
  // XCD chunk swizzle (bijective: 7168 % 8 == 0)
  const int flat = blockIdx.x + 28 * (blockIdx.y + 32 * blockIdx.z);
  const int w = (flat & 7) * 896 + (flat >> 3);
  const int bx = w % 28, by = (w / 28) & 31, e = w / 896;
  const int cn = cnt[e];
  const int m0 = by * 128;
  if (m0 >= cn) return;
  int padoff = 0;
  for (int i = 0; i < e; ++i) padoff += (cnt[i] + 127) & ~127;
  const int n0 = bx * 128;
  __shared__ unsigned short As[3][4096], Bg[3][4096], Bu[3][4096];
  const int tid = threadIdx.x, wid = tid >> 6, lane = tid & 63;
  const int wm = (wid >> 2) * 64, wn = (wid & 3) * 32;
  const int fr = lane & 15, fg = lane >> 4;
  const int srow = tid >> 2;                               // 0..127
  const int scol = (((tid & 3) ^ ((tid >> 3) & 3))) * 8;   // swizzled source chunk
  const int lr = m0 + srow;
  const int tkr = (lr < cn) ? tok[e * 4096 + lr] : 0;
  const unsigned short* ga = H2 + (long)tkr * 1024 + scol;
  const unsigned short* gb = WG + (long)e * 3584 * 1024 + (long)(n0 + srow) * 1024 + scol;
  const unsigned short* gu = WU + (long)e * 3584 * 1024 + (long)(n0 + srow) * 1024 + scol;
#define GU_STAGE(s, b)                                                         \
  do {                                                                         \
    const int ko = (s) * 32;                                                   \
    GL16(ga + ko, (char*)As[b] + wid * 1024);                                  \
    GL16(gb + ko, (char*)Bg[b] + wid * 1024);                                  \
    GL16(gu + ko, (char*)Bu[b] + wid * 1024);                                  \
  } while (0)
  f32x4 ag[4][2] = {}, au[4][2] = {};
  GU_STAGE(0, 0);
  GU_STAGE(1, 1);
  PIPE_SYNC(3);
  for (int t = 0; t < 32; ++t) {
    const int cb = t % 3;
    if (t + 2 < 32) GU_STAGE(t + 2, (t + 2) % 3);
    const unsigned short* As_ = As[cb];
    const unsigned short* Bg_ = Bg[cb];
    const unsigned short* Bu_ = Bu[cb];
    bf16x8 af[4], bgf[2], buf_[2];
#pragma unroll
    for (int i = 0; i < 4; ++i) af[i] = *(const bf16x8*)&As_[sw32(wm + i * 16 + fr, fg)];
#pragma unroll
    for (int j = 0; j < 2; ++j) {
      const int oB = sw32(wn + j * 16 + fr, fg);
      bgf[j] = *(const bf16x8*)&Bg_[oB];
      buf_[j] = *(const bf16x8*)&Bu_[oB];
    }
    SETPRIO(1);
#pragma unroll
    for (int i = 0; i < 4; ++i)
#pragma unroll
      for (int j = 0; j < 2; ++j) {
        ag[i][j] = MFMA16(af[i], bgf[j], ag[i][j]);
        au[i][j] = MFMA16(af[i], buf_[j], au[i][j]);
      }
    SETPRIO(0);
    if (t + 2 < 32) PIPE_SYNC(3);
    else if (t + 1 < 32) PIPE_SYNC(0);
  }
#undef GU_STAGE
  const int cr = fg * 4;
#pragma unroll
  for (int i = 0; i < 4; ++i)
#pragma unroll
    for (int j = 0; j < 2; ++j)
#pragma unroll
      for (int rr = 0; rr < 4; ++rr) {
        const int row = wm + i * 16 + cr + rr;  // tile-local
        const int col = n0 + wn + j * 16 + fr;
        const float gv = ag[i][j][rr];
        const float sg = gv / (1.f + __expf(-gv));  // silu
        act[(long)(padoff + m0 + row) * 3584 + col] = f2bf(sg * au[i][j][rr]);
      }
}

// MoE down GEMM + scatter: out[tok] += w * (act @ Wd^T)
// R6-exact: 512 threads (8 waves, 2Mx4N), wave 64x32, 3-stage vmcnt(2),
// XCD chunk swizzle (nwg=2048, 256/XCD = 1 expert). Twice-verified best.
__global__ __launch_bounds__(512, 4) void down_kernel(const unsigned short* __restrict__ act,
                                                      const unsigned short* __restrict__ WD,
                                                      const int* __restrict__ tok,
                                                      const float* __restrict__ wgt,
                                                      const int* __restrict__ cnt,
                                                      float* __restrict__ out) {
  const int flat = blockIdx.x + 8 * (blockIdx.y + 32 * blockIdx.z);
  const int w = (flat & 7) * 256 + (flat >> 3);
  const int bx = w & 7, by = (w >> 3) & 31, e = w >> 8;
  const int cn = cnt[e];
  const int m0 = by * 128;
  if (m0 >= cn) return;
  int padoff = 0;
  for (int i = 0; i < e; ++i) padoff += (cnt[i] + 127) & ~127;
  const int n0 = bx * 128;
  __shared__ unsigned short As[3][4096], Bs[3][4096];
  const int tid = threadIdx.x, wid = tid >> 6, lane = tid & 63;
  const int wm = (wid >> 2) * 64, wn = (wid & 3) * 32;
  const int fr = lane & 15, fg = lane >> 4;
  const int srow = tid >> 2;                               // 0..127
  const int scol = (((tid & 3) ^ ((tid >> 3) & 3))) * 8;   // swizzled source chunk
  const unsigned short* ga = act + (long)(padoff + m0 + srow) * 3584 + scol;
  const unsigned short* gb = WD + (long)e * 1024 * 3584 + (long)(n0 + srow) * 3584 + scol;
#define DN_STAGE(s, b)                                                         \
  do {                                                                         \
    const int ko = (s) * 32;                                                   \
    GL16(ga + ko, (char*)As[b] + wid * 1024);                                  \
    GL16(gb + ko, (char*)Bs[b] + wid * 1024);                                  \
  } while (0)
  f32x4 acc[4][2] = {};
  DN_STAGE(0, 0);
  DN_STAGE(1, 1);
  PIPE_SYNC(2);
  for (int t = 0; t < 112; ++t) {
    const int cb = t % 3;
    if (t + 2 < 112) DN_STAGE(t + 2, (t + 2) % 3);
    const unsigned short* As_ = As[cb];
    const unsigned short* Bs_ = Bs[cb];
    bf16x8 af[4], bf_[2];
#pragma unroll
    for (int i = 0; i < 4; ++i) af[i] = *(const bf16x8*)&As_[sw32(wm + i * 16 + fr, fg)];
#pragma unroll
    for (int j = 0; j < 2; ++j) bf_[j] = *(const bf16x8*)&Bs_[sw32(wn + j * 16 + fr, fg)];
    SETPRIO(1);
#pragma unroll
    for (int i = 0; i < 4; ++i)
#pragma unroll
      for (int j = 0; j < 2; ++j)
        acc[i][j] = MFMA16(af[i], bf_[j], acc[i][j]);
    SETPRIO(0);
    if (t + 2 < 112) PIPE_SYNC(2);
    else if (t + 1 < 112) PIPE_SYNC(0);
  }
#undef DN_STAGE
  const int cr = fg * 4;
#pragma unroll
  for (int i = 0; i < 4; ++i)
#pragma unroll
    for (int rr = 0; rr < 4; ++rr) {
      const int lrow = m0 + wm + i * 16 + cr + rr;
      if (lrow < cn) {
        const int tk = tok[e * 4096 + lrow];
        const float wv_ = wgt[e * 4096 + lrow];
#pragma unroll
        for (int j = 0; j < 2; ++j)
          atomicAdd(&out[(long)tk * 1024 + n0 + wn + j * 16 + fr], wv_ * acc[i][j][rr]);
      }
    }
}

// ---------------------------------------------------------------------------
extern "C" void kernel_launch(void* const* d_in, const int* in_sizes, int n_in,
                              void* d_out, int out_size, void* d_ws, size_t ws_size,
                              hipStream_t stream) {
  (void)in_sizes; (void)n_in; (void)out_size;
  if (ws_size < WS_NEED) {
    fprintf(stderr, "kernel_launch: ws too small: %zu < %zu\n", ws_size, (size_t)WS_NEED);
  }
  const float* x    = (const float*)d_in[0];
  const float* n1s  = (const float*)d_in[1];
  const float* n2s  = (const float*)d_in[2];
  const float* wq   = (const float*)d_in[3];
  const float* wk   = (const float*)d_in[4];
  const float* wv   = (const float*)d_in[5];
  const float* wo   = (const float*)d_in[6];
  const float* wrt  = (const float*)d_in[7];
  const float* wg   = (const float*)d_in[8];
  const float* wu   = (const float*)d_in[9];
  const float* wd   = (const float*)d_in[10];
  float* out = (float*)d_out;
  char* W = (char*)d_ws;

  unsigned short* WQH = (unsigned short*)(W + O_WQKVT_HI);
  unsigned short* WQL = (unsigned short*)(W + O_WQKVT_LO);
  unsigned short* WOH = (unsigned short*)(W + O_WOT_HI);
  unsigned short* WOL = (unsigned short*)(W + O_WOT_LO);
  unsigned short* WGT = (unsigned short*)(W + O_WGT);
  unsigned short* WUT = (unsigned short*)(W + O_WUT);
  unsigned short* WDT = (unsigned short*)(W + O_WDT);
  unsigned short* H2  = (unsigned short*)(W + O_H2);
  int* TOK    = (int*)(W + O_TOK);
  float* WGTL = (float*)(W + O_WGTL);
  int* CNT    = (int*)(W + O_CNT);
  unsigned short* HSH = (unsigned short*)(W + O_HSHI);
  unsigned short* HSL = (unsigned short*)(W + O_HSLO);
  float* QKV = (float*)(W + O_QKV);
  unsigned short* QHI = (unsigned short*)(W + O_QHI);
  unsigned short* QLO = (unsigned short*)(W + O_QLO);
  unsigned short* KHI = (unsigned short*)(W + O_KHI);
  unsigned short* KLO = (unsigned short*)(W + O_KLO);
  unsigned short* VTH = (unsigned short*)(W + O_VTH);
  unsigned short* VTL = (unsigned short*)(W + O_VTL);
  unsigned short* AHI = (unsigned short*)(W + O_AHI);
  unsigned short* ALO = (unsigned short*)(W + O_ALO);
  float* XATTN = (float*)(W + O_XATTN);
  unsigned short* ACT = (unsigned short*)(W + O_ACT);
  float2* ROPET = (float2*)(W + O_ROPET);  // aliases AHI (dead until attn)

  // RoPE table + cnt zeroing (table region overwritten later by attn's AHI)
  rope_table_kernel<<<256, 256, 0, stream>>>(ROPET, CNT);
  // RMSNorm1 -> split hs
  rmsnorm_kernel<<<4096, 256, 0, stream>>>(x, n1s, HSH, HSL);
  // weight transposes (per call; bf16 [N][K] layouts)
  transpose_cvt_split<<<dim3(16, 16, 1), 256, 0, stream>>>(wq, WQH, WQL, 1024, 1024);
  transpose_cvt_split<<<dim3(4, 16, 1), 256, 0, stream>>>(wk, WQH + 1024L * 1024, WQL + 1024L * 1024, 1024, 256);
  transpose_cvt_split<<<dim3(4, 16, 1), 256, 0, stream>>>(wv, WQH + 1280L * 1024, WQL + 1280L * 1024, 1024, 256);
  transpose_cvt_split<<<dim3(16, 16, 1), 256, 0, stream>>>(wo, WOH, WOL, 1024, 1024);
  transpose_cvt<<<dim3(56, 16, 8), 256, 0, stream>>>(wg, WGT, 1024, 3584, 1024L * 3584, 3584L * 1024);
  transpose_cvt<<<dim3(56, 16, 8), 256, 0, stream>>>(wu, WUT, 1024, 3584, 1024L * 3584, 3584L * 1024);
  transpose_cvt<<<dim3(16, 56, 8), 256, 0, stream>>>(wd, WDT, 3584, 1024, 3584L * 1024, 1024L * 3584);
  // QKV projection (split GEMM, f32 out)
  gemm_split<<<dim3(12, 32, 1), 256, 0, stream>>>(HSH, HSL, WQH, WQL, nullptr, QKV, 4096, 1536, 1024);
  // RoPE + split (table-driven); V transpose + split
  rope_kernel<<<4096, 256, 0, stream>>>(QKV, ROPET, QHI, QLO, KHI, KLO);
  vt_split_kernel<<<dim3(32, 4, 2), 256, 0, stream>>>(QKV, VTH, VTL);
  // attention (overwrites the table region with AHI — table already consumed)
  attn_kernel<<<dim3(32, 16, 2), 256, 0, stream>>>(QHI, QLO, KHI, KLO, VTH, VTL, AHI, ALO);
  // out projection + residual
  gemm_split<<<dim3(8, 32, 1), 256, 0, stream>>>(AHI, ALO, WOH, WOL, x, XATTN, 4096, 1024, 1024);
  // fused: residual init + RMSNorm2 -> H2 + router -> logits/lists
  router_fused_kernel<<<4096, 256, 0, stream>>>(XATTN, n2s, wrt, out + 4194304, H2, out,
                                                TOK, WGTL, CNT);
  gateup_kernel<<<dim3(28, 32, 8), 512, 0, stream>>>(H2, WGT, WUT, TOK, CNT, ACT);
  down_kernel<<<dim3(8, 32, 8), 512, 0, stream>>>(ACT, WDT, TOK, WGTL, CNT, out);
}

// Round 11
// 671.830 us; speedup vs baseline: 1.0629x; 1.0098x over previous
//
#include <hip/hip_runtime.h>
#include <hip/hip_bf16.h>
#include <cstdio>

// ---------------------------------------------------------------------------
// MixtralTransformerDecoder: B=2 S=2048 H=1024 NQ=16 NKV=4 HD=64 I=3584 E=8
// TOP_K=2, sliding window 512.
// Split-bf16 (hi+lo) MFMA upstream of the router; plain bf16 MFMA for experts.
// R11: rope stores widened to 4B (bit-identical), 4 small weight transposes
// merged into one z-indexed launch. All else identical to R10 (678 us).
// ---------------------------------------------------------------------------

typedef __bf16 bf16x8 __attribute__((ext_vector_type(8)));
typedef float f32x4 __attribute__((ext_vector_type(4)));

#define MFMA16(a, b, c) __builtin_amdgcn_mfma_f32_16x16x32_bf16((a), (b), (c), 0, 0, 0)
#define GL16(g, l)                                                             \
  __builtin_amdgcn_global_load_lds(                                            \
      (const __attribute__((address_space(1))) void*)(g),                      \
      (__attribute__((address_space(3))) void*)(l), 16, 0, 0)
#define WAIT_VM0() asm volatile("s_waitcnt vmcnt(0)" ::: "memory")
#define SETPRIO(n) __builtin_amdgcn_s_setprio(n)
// counted-vmcnt + raw barrier + compiler fence (T4; __syncthreads would drain)
#define PIPE_SYNC(n)                                                           \
  do {                                                                         \
    asm volatile("s_waitcnt vmcnt(" #n ")" ::: "memory");                      \
    __builtin_amdgcn_s_barrier();                                              \
    asm volatile("" ::: "memory");                                             \
  } while (0)

__device__ __forceinline__ unsigned short f2bf(float f) {
  unsigned u = __builtin_bit_cast(unsigned, f);
  u += 0x7fffu + ((u >> 16) & 1u);
  return (unsigned short)(u >> 16);
}
__device__ __forceinline__ float bf2f(unsigned short h) {
  unsigned u = ((unsigned)h) << 16;
  return __builtin_bit_cast(float, u);
}
// swizzled element offset for [row][32 bf16] LDS tiles (64B rows, 4 chunks)
__device__ __forceinline__ int sw32(int row, int chunk) {
  return row * 32 + ((chunk ^ ((row >> 1) & 3)) * 8);
}

// ---------------------------------------------------------------------------
// Workspace layout (bytes)
// ---------------------------------------------------------------------------
static constexpr size_t O_WQKVT_HI = 0;                           // [1536][1024] bf16
static constexpr size_t SZ_WQKVT   = 1536UL * 1024 * 2;
static constexpr size_t O_WQKVT_LO = O_WQKVT_HI + SZ_WQKVT;
static constexpr size_t O_WOT_HI   = O_WQKVT_LO + SZ_WQKVT;       // [1024][1024] bf16
static constexpr size_t SZ_WOT     = 1024UL * 1024 * 2;
static constexpr size_t O_WOT_LO   = O_WOT_HI + SZ_WOT;
static constexpr size_t O_WGT      = O_WOT_LO + SZ_WOT;           // [8][3584][1024] bf16
static constexpr size_t SZ_WE      = 8UL * 3584 * 1024 * 2;
static constexpr size_t O_WUT      = O_WGT + SZ_WE;
static constexpr size_t O_WDT      = O_WUT + SZ_WE;               // [8][1024][3584] bf16
static constexpr size_t O_H2       = O_WDT + SZ_WE;               // [4096][1024] bf16
static constexpr size_t SZ_BF_TH   = 4096UL * 1024 * 2;
static constexpr size_t O_TOK      = O_H2 + SZ_BF_TH;             // [8][4096] i32
static constexpr size_t O_WGTL     = O_TOK + 8UL * 4096 * 4;      // [8][4096] f32
static constexpr size_t O_CNT      = O_WGTL + 8UL * 4096 * 4;     // [8] i32
static constexpr size_t O_DYN      = O_CNT + 256;
// DYN region (dead before MoE; ACT aliases its head)
static constexpr size_t O_HSHI  = O_DYN;
static constexpr size_t O_HSLO  = O_HSHI + SZ_BF_TH;
static constexpr size_t O_QKV   = O_HSLO + SZ_BF_TH;              // [4096][1536] f32
static constexpr size_t O_QHI   = O_QKV + 4096UL * 1536 * 4;      // [2][16][2048][64] bf16
static constexpr size_t O_QLO   = O_QHI + SZ_BF_TH;
static constexpr size_t O_KHI   = O_QLO + SZ_BF_TH;               // [2][4][2048][64] bf16
static constexpr size_t SZ_BF_T256 = 4096UL * 256 * 2;
static constexpr size_t O_KLO   = O_KHI + SZ_BF_T256;
static constexpr size_t O_VTH   = O_KLO + SZ_BF_T256;             // [2][4][64][2048] bf16
static constexpr size_t O_VTL   = O_VTH + SZ_BF_T256;
static constexpr size_t O_AHI   = O_VTL + SZ_BF_T256;             // [4096][1024] bf16
static constexpr size_t O_ALO   = O_AHI + SZ_BF_TH;
static constexpr size_t O_XATTN = O_ALO + SZ_BF_TH;               // [4096][1024] f32
static constexpr size_t O_END   = O_XATTN + 4096UL * 1024 * 4;
static constexpr size_t O_ACT   = O_DYN;   // [<=9208][3584] bf16 alias (66MB, before XATTN)
// RoPE table [2048][32] float2 = 512KB: aliases O_AHI (dead until attn_kernel
// writes AHI, which happens after rope_kernel has consumed the table).
static constexpr size_t O_ROPET = O_AHI;
static constexpr size_t WS_NEED = O_END;

// ---------------------------------------------------------------------------
// small kernels
// ---------------------------------------------------------------------------
// RoPE cos/sin table: tbl[s][p] = (cos(s*inv_p), sin(s*inv_p)), bit-identical
// expressions to the original in-kernel computation. Also zeroes expert counts.
__global__ __launch_bounds__(256) void rope_table_kernel(float2* __restrict__ tbl,
                                                         int* __restrict__ cnt) {
  const int i = blockIdx.x * 256 + threadIdx.x;  // 65536 = 2048 s x 32 p
  const int s = i >> 5, p = i & 31;
  const float inv = (float)exp2(-(double)p * 0.4152410118609203);  // 10000^(-p/32)
  float sn, cs;
  sincosf((float)s * inv, &sn, &cs);
  tbl[i] = make_float2(cs, sn);
  if (i < 8) cnt[i] = 0;
}

// RMSNorm: x[4096][1024] f32 -> hi (+ optional lo) bf16
__global__ __launch_bounds__(256) void rmsnorm_kernel(const float* __restrict__ x,
                                                      const float* __restrict__ scale,
                                                      unsigned short* __restrict__ hi,
                                                      unsigned short* __restrict__ lo) {
  const int t = blockIdx.x, tid = threadIdx.x;
  const float4 v = *(const float4*)&x[(long)t * 1024 + tid * 4];
  float ss = v.x * v.x + v.y * v.y + v.z * v.z + v.w * v.w;
#pragma unroll
  for (int off = 32; off >= 1; off >>= 1) ss += __shfl_down(ss, off);
  __shared__ float red[4];
  if ((tid & 63) == 0) red[tid >> 6] = ss;
  __syncthreads();
  const float r = rsqrtf((red[0] + red[1] + red[2] + red[3]) * (1.0f / 1024.0f) + 1e-5f);
  const float4 sc = *(const float4*)&scale[tid * 4];
  float o[4] = {v.x * r * sc.x, v.y * r * sc.y, v.z * r * sc.z, v.w * r * sc.w};
  ushort4 hh, ll;
  unsigned short* hp = (unsigned short*)&hh;
  unsigned short* lp = (unsigned short*)&ll;
#pragma unroll
  for (int i = 0; i < 4; ++i) {
    hp[i] = f2bf(o[i]);
    lp[i] = f2bf(o[i] - bf2f(hp[i]));
  }
  *(ushort4*)&hi[(long)t * 1024 + tid * 4] = hh;
  if (lo) *(ushort4*)&lo[(long)t * 1024 + tid * 4] = ll;
}

// transpose+convert: src f32 [R][C] -> dst bf16 [C][R]
__global__ __launch_bounds__(256) void transpose_cvt(const float* __restrict__ src,
                                                     unsigned short* __restrict__ dst,
                                                     int R, int C, long zsrc, long zdst) {
  src += (long)blockIdx.z * zsrc;
  dst += (long)blockIdx.z * zdst;
  const int c0 = blockIdx.x * 64, r0 = blockIdx.y * 64, tid = threadIdx.x;
  __shared__ float tb[64][65];
#pragma unroll
  for (int p = 0; p < 4; ++p) {
    const int r = p * 16 + (tid >> 4), c = (tid & 15) * 4;
    const float4 v = *(const float4*)&src[(long)(r0 + r) * C + c0 + c];
    tb[c + 0][r] = v.x; tb[c + 1][r] = v.y; tb[c + 2][r] = v.z; tb[c + 3][r] = v.w;
  }
  __syncthreads();
  const int dr = tid >> 2, s0 = (tid & 3) * 16;
  __align__(16) unsigned short tmp[16];
#pragma unroll
  for (int i = 0; i < 16; ++i) tmp[i] = f2bf(tb[dr][s0 + i]);
  const long o = (long)(c0 + dr) * R + r0 + s0;
  *(uint4*)&dst[o] = *(const uint4*)&tmp[0];
  *(uint4*)&dst[o + 8] = *(const uint4*)&tmp[8];
}

// merged transpose+convert+split for the 4 attention weight mats (z selects).
// z=0: wq [1024][1024]; z=1: wk [1024][256]; z=2: wv [1024][256]; z=3: wo.
__global__ __launch_bounds__(256) void transpose_cvt_split4(const float* __restrict__ wq,
                                                            const float* __restrict__ wk,
                                                            const float* __restrict__ wv,
                                                            const float* __restrict__ wo,
                                                            unsigned short* __restrict__ WQH,
                                                            unsigned short* __restrict__ WQL,
                                                            unsigned short* __restrict__ WOH,
                                                            unsigned short* __restrict__ WOL) {
  const int z = blockIdx.z;
  const int C = (z == 1 || z == 2) ? 256 : 1024;  // src cols (dst rows)
  if (blockIdx.x * 64 >= C) return;
  const float* src;
  unsigned short *dh, *dl;
  if (z == 0)      { src = wq; dh = WQH;               dl = WQL; }
  else if (z == 1) { src = wk; dh = WQH + 1024L * 1024; dl = WQL + 1024L * 1024; }
  else if (z == 2) { src = wv; dh = WQH + 1280L * 1024; dl = WQL + 1280L * 1024; }
  else             { src = wo; dh = WOH;               dl = WOL; }
  const int R = 1024;
  const int c0 = blockIdx.x * 64, r0 = blockIdx.y * 64, tid = threadIdx.x;
  __shared__ float tb[64][65];
#pragma unroll
  for (int p = 0; p < 4; ++p) {
    const int r = p * 16 + (tid >> 4), c = (tid & 15) * 4;
    const float4 v = *(const float4*)&src[(long)(r0 + r) * C + c0 + c];
    tb[c + 0][r] = v.x; tb[c + 1][r] = v.y; tb[c + 2][r] = v.z; tb[c + 3][r] = v.w;
  }
  __syncthreads();
  const int dr = tid >> 2, s0 = (tid & 3) * 16;
  __align__(16) unsigned short th[16], tl[16];
#pragma unroll
  for (int i = 0; i < 16; ++i) {
    const float f = tb[dr][s0 + i];
    th[i] = f2bf(f);
    tl[i] = f2bf(f - bf2f(th[i]));
  }
  const long o = (long)(c0 + dr) * R + r0 + s0;
  *(uint4*)&dh[o] = *(const uint4*)&th[0];
  *(uint4*)&dh[o + 8] = *(const uint4*)&th[8];
  *(uint4*)&dl[o] = *(const uint4*)&tl[0];
  *(uint4*)&dl[o + 8] = *(const uint4*)&tl[8];
}

// ---------------------------------------------------------------------------
// split-bf16 GEMM: C[M][N] = (Ahi+Alo)[M][K] @ (Bhi+Blo)[N][K]^T (+resid)
// 128x128 tile, BK=32, dbuf prefetch + swizzle + setprio (R6 form).
// ---------------------------------------------------------------------------
__global__ __launch_bounds__(256) void gemm_split(const unsigned short* __restrict__ Ahi,
                                                  const unsigned short* __restrict__ Alo,
                                                  const unsigned short* __restrict__ Bhi,
                                                  const unsigned short* __restrict__ Blo,
                                                  const float* __restrict__ resid,
                                                  float* __restrict__ C,
                                                  int M, int N, int K) {
  __shared__ unsigned short Ash[2][4096], Asl[2][4096], Bsh[2][4096], Bsl[2][4096];
  const int tid = threadIdx.x, wid = tid >> 6, lane = tid & 63;
  const int m0 = blockIdx.y * 128, n0 = blockIdx.x * 128;
  const int wm = (wid >> 1) * 64, wn = (wid & 1) * 64;
  const int fr = lane & 15, fg = lane >> 4;
  const int srow = tid >> 2;
  const int scol = (((tid & 3) ^ ((tid >> 3) & 3))) * 8;  // swizzled source chunk
  const long aoff = (long)(m0 + srow) * K + scol;
  const long boff = (long)(n0 + srow) * K + scol;
  const long h64 = 64L * K;
  char* a0 = (char*)Ash[0] + wid * 1024; char* a1 = (char*)Ash[1] + wid * 1024;
  char* al0 = (char*)Asl[0] + wid * 1024; char* al1 = (char*)Asl[1] + wid * 1024;
  char* b0 = (char*)Bsh[0] + wid * 1024; char* b1 = (char*)Bsh[1] + wid * 1024;
  char* bl0 = (char*)Bsl[0] + wid * 1024; char* bl1 = (char*)Bsl[1] + wid * 1024;
#define GS_STAGE(koff, pah_, pal_, pbh_, pbl_)                                 \
  do {                                                                         \
    GL16(Ahi + aoff + (koff), (pah_));                                         \
    GL16(Ahi + aoff + h64 + (koff), (pah_) + 4096);                            \
    GL16(Alo + aoff + (koff), (pal_));                                         \
    GL16(Alo + aoff + h64 + (koff), (pal_) + 4096);                            \
    GL16(Bhi + boff + (koff), (pbh_));                                         \
    GL16(Bhi + boff + h64 + (koff), (pbh_) + 4096);                            \
    GL16(Blo + boff + (koff), (pbl_));                                         \
    GL16(Blo + boff + h64 + (koff), (pbl_) + 4096);                            \
  } while (0)
  f32x4 acc[4][4] = {};
  GS_STAGE(0, a0, al0, b0, bl0);
  WAIT_VM0();
  __syncthreads();
  int cur = 0;
  for (int k0 = 0; k0 < K; k0 += 32) {
    const int kn = k0 + 32;
    if (kn < K) {
      if (cur) GS_STAGE(kn, a0, al0, b0, bl0);
      else     GS_STAGE(kn, a1, al1, b1, bl1);
    }
    const unsigned short* As_ = Ash[cur];
    const unsigned short* Al_ = Asl[cur];
    const unsigned short* Bs_ = Bsh[cur];
    const unsigned short* Bl_ = Bsl[cur];
    bf16x8 ah[4], al[4], bh[4], bl[4];
#pragma unroll
    for (int i = 0; i < 4; ++i) {
      const int oA = sw32(wm + i * 16 + fr, fg);
      const int oB = sw32(wn + i * 16 + fr, fg);
      ah[i] = *(const bf16x8*)&As_[oA];
      al[i] = *(const bf16x8*)&Al_[oA];
      bh[i] = *(const bf16x8*)&Bs_[oB];
      bl[i] = *(const bf16x8*)&Bl_[oB];
    }
    SETPRIO(1);
#pragma unroll
    for (int i = 0; i < 4; ++i)
#pragma unroll
      for (int j = 0; j < 4; ++j) {
        acc[i][j] = MFMA16(al[i], bh[j], acc[i][j]);
        acc[i][j] = MFMA16(ah[i], bl[j], acc[i][j]);
        acc[i][j] = MFMA16(ah[i], bh[j], acc[i][j]);
      }
    SETPRIO(0);
    WAIT_VM0();
    __syncthreads();
    cur ^= 1;
  }
#undef GS_STAGE
  const int cr = fg * 4;
#pragma unroll
  for (int i = 0; i < 4; ++i)
#pragma unroll
    for (int j = 0; j < 4; ++j)
#pragma unroll
      for (int rr = 0; rr < 4; ++rr) {
        const int row = m0 + wm + i * 16 + cr + rr;
        const int col = n0 + wn + j * 16 + fr;
        float v = acc[i][j][rr];
        if (resid) v += resid[(long)row * N + col];
        C[(long)row * N + col] = v;
      }
}

// ---------------------------------------------------------------------------
// RoPE + split: qkv f32 [4096][1536] -> Qhi/Qlo (scaled 1/8), Khi/Klo
// Table-driven cos/sin; 4-byte paired stores (bit-identical values).
// ---------------------------------------------------------------------------
__global__ __launch_bounds__(256) void rope_kernel(const float* __restrict__ qkv,
                                                   const float2* __restrict__ tbl,
                                                   unsigned short* __restrict__ Qh,
                                                   unsigned short* __restrict__ Ql,
                                                   unsigned short* __restrict__ Kh,
                                                   unsigned short* __restrict__ Kl) {
  const int t = blockIdx.x, b = t >> 11, s = t & 2047;
  const float* src = qkv + (long)t * 1536;
  const float2* trow = tbl + (s << 5);
  for (int task = threadIdx.x; task < 640; task += 256) {
    const int head = task >> 5, p = task & 31;
    const float* hp = src + head * 64;
    const float2 t2 = trow[p];
    const float cs = t2.x, sn = t2.y;
    const float x0 = hp[2 * p], x1 = hp[2 * p + 1], xa = hp[p], xb = hp[32 + p];
    float o0 = x0 * cs - xb * sn;
    float o1 = x1 * cs + xa * sn;
    unsigned short *dh, *dl;
    long base;
    if (head < 16) {
      o0 *= 0.125f; o1 *= 0.125f;  // fold 1/sqrt(64) into Q
      base = ((long)(b * 16 + head) * 2048 + s) * 64;
      dh = Qh; dl = Ql;
    } else {
      base = ((long)(b * 4 + (head - 16)) * 2048 + s) * 64;
      dh = Kh; dl = Kl;
    }
    const unsigned short h0 = f2bf(o0);
    const unsigned short h1 = f2bf(o1);
    const unsigned short l0 = f2bf(o0 - bf2f(h0));
    const unsigned short l1 = f2bf(o1 - bf2f(h1));
    // base + 2p is even -> 4-byte aligned paired stores
    *(unsigned*)&dh[base + 2 * p] = ((unsigned)h1 << 16) | h0;
    *(unsigned*)&dl[base + 2 * p] = ((unsigned)l1 << 16) | l0;
  }
}

// V transpose+split: -> Vth/Vtl [2][4][64][2048] bf16
__global__ __launch_bounds__(256) void vt_split_kernel(const float* __restrict__ qkv,
                                                       unsigned short* __restrict__ Vh,
                                                       unsigned short* __restrict__ Vl) {
  const int st = blockIdx.x * 64, g = blockIdx.y, b = blockIdx.z, tid = threadIdx.x;
  __shared__ float tb[64][65];
  const float* src = qkv + (long)(b * 2048 + st) * 1536 + 1280 + g * 64;
#pragma unroll
  for (int p = 0; p < 4; ++p) {
    const int r = p * 16 + (tid >> 4), c = (tid & 15) * 4;
    const float4 v = *(const float4*)&src[(long)r * 1536 + c];
    tb[c + 0][r] = v.x; tb[c + 1][r] = v.y; tb[c + 2][r] = v.z; tb[c + 3][r] = v.w;
  }
  __syncthreads();
  const int dr = tid >> 2, s0 = (tid & 3) * 16;
  __align__(16) unsigned short hh[16], ll[16];
#pragma unroll
  for (int i = 0; i < 16; ++i) {
    const float f = tb[dr][s0 + i];
    hh[i] = f2bf(f);
    ll[i] = f2bf(f - bf2f(hh[i]));
  }
  const long dst = ((long)(b * 4 + g) * 64 + dr) * 2048 + st + s0;
  *(uint4*)&Vh[dst] = *(const uint4*)&hh[0];
  *(uint4*)&Vh[dst + 8] = *(const uint4*)&hh[8];
  *(uint4*)&Vl[dst] = *(const uint4*)&ll[0];
  *(uint4*)&Vl[dst + 8] = *(const uint4*)&ll[8];
}

// ---------------------------------------------------------------------------
// Flash attention, split-bf16 MFMA, sliding window 512, causal (R6 form).
// ---------------------------------------------------------------------------
__global__ __launch_bounds__(256) void attn_kernel(const unsigned short* __restrict__ Qh,
                                                   const unsigned short* __restrict__ Ql,
                                                   const unsigned short* __restrict__ Kh,
                                                   const unsigned short* __restrict__ Kl,
                                                   const unsigned short* __restrict__ Vh,
                                                   const unsigned short* __restrict__ Vl,
                                                   unsigned short* __restrict__ Ohi,
                                                   unsigned short* __restrict__ Olo) {
  const int qt = blockIdx.x, h = blockIdx.y, b = blockIdx.z, g = h >> 2;
  const int q0 = qt * 64, tid = threadIdx.x, wid = tid >> 6, lane = tid & 63;
  const int fr = lane & 15, fg = lane >> 4;
  __shared__ unsigned short Ksh[2][2048], Ksl[2][2048];  // [32 keys][64 d]
  __shared__ unsigned short Vsh[2][2048], Vsl[2][2048];  // [64 d][32 keys]
  __shared__ unsigned short Ph[4][512], Pl[4][512];      // per-wave [16][32]

  const long qoff = ((long)(b * 16 + h) * 2048 + q0 + wid * 16 + fr) * 64;
  bf16x8 qh[2], ql[2];
  qh[0] = *(const bf16x8*)&Qh[qoff + fg * 8];
  qh[1] = *(const bf16x8*)&Qh[qoff + 32 + fg * 8];
  ql[0] = *(const bf16x8*)&Ql[qoff + fg * 8];
  ql[1] = *(const bf16x8*)&Ql[qoff + 32 + fg * 8];

  f32x4 o[4] = {};
  float mrow[4], lrow[4];
#pragma unroll
  for (int rr = 0; rr < 4; ++rr) { mrow[rr] = -1e30f; lrow[rr] = 0.f; }

  const int jmin = (q0 >= 511) ? (q0 - 511) : 0;
  const int jt0 = jmin & ~31;
  const long kbase = ((long)(b * 4 + g) * 2048) * 64;
  const long vbase = ((long)(b * 4 + g) * 64) * 2048;
  const int srK = tid >> 3;                                  // 0..31
  const int scK = (((tid & 7) ^ (srK & 7))) * 8;             // swizzled K source chunk
  const int srV = tid >> 2;                                  // 0..63
  const int scV = (((tid & 3) ^ ((srV >> 1) & 3))) * 8;      // swizzled V source chunk
  char* kh0 = (char*)Ksh[0] + wid * 1024; char* kh1 = (char*)Ksh[1] + wid * 1024;
  char* kl0 = (char*)Ksl[0] + wid * 1024; char* kl1 = (char*)Ksl[1] + wid * 1024;
  char* vh0 = (char*)Vsh[0] + wid * 1024; char* vh1 = (char*)Vsh[1] + wid * 1024;
  char* vl0 = (char*)Vsl[0] + wid * 1024; char* vl1 = (char*)Vsl[1] + wid * 1024;
#define ATTN_STAGE(jt_, kh_, kl_, vh_, vl_)                                    \
  do {                                                                         \
    const long ko = kbase + (long)((jt_) + srK) * 64 + scK;                    \
    GL16(Kh + ko, (kh_));                                                      \
    GL16(Kl + ko, (kl_));                                                      \
    const long vo = vbase + (long)srV * 2048 + (jt_) + scV;                    \
    GL16(Vh + vo, (vh_));                                                      \
    GL16(Vl + vo, (vl_));                                                      \
  } while (0)

  ATTN_STAGE(jt0, kh0, kl0, vh0, vl0);
  WAIT_VM0();
  __syncthreads();
  int cur = 0;
  for (int jt = jt0; jt < q0 + 64; jt += 32) {
    const int jn = jt + 32;
    if (jn < q0 + 64) {
      if (cur) ATTN_STAGE(jn, kh0, kl0, vh0, vl0);
      else     ATTN_STAGE(jn, kh1, kl1, vh1, vl1);
    }
    const unsigned short* KH = Ksh[cur];
    const unsigned short* KL = Ksl[cur];
    const unsigned short* VH = Vsh[cur];
    const unsigned short* VL = Vsl[cur];

    // ---- QK^T (3-term split); K rows 128B -> chunk ^= row&7 ----
    f32x4 sf[2] = {};
#pragma unroll
    for (int cf = 0; cf < 2; ++cf)
#pragma unroll
      for (int dc = 0; dc < 2; ++dc) {
        const int row = cf * 16 + fr;
        const int off = row * 64 + (((dc * 4 + fg) ^ (row & 7)) * 8);
        const bf16x8 kh = *(const bf16x8*)&KH[off];
        const bf16x8 kl = *(const bf16x8*)&KL[off];
        sf[cf] = MFMA16(ql[dc], kh, sf[cf]);
        sf[cf] = MFMA16(qh[dc], kl, sf[cf]);
        sf[cf] = MFMA16(qh[dc], kh, sf[cf]);
      }

    // ---- mask + online softmax ----
    float sv[2][4];
#pragma unroll
    for (int cf = 0; cf < 2; ++cf) {
      const int j = jt + cf * 16 + fr;
#pragma unroll
      for (int rr = 0; rr < 4; ++rr) {
        const int q = q0 + wid * 16 + fg * 4 + rr;
        const bool ok = (j <= q) && (j >= q - 511);
        sv[cf][rr] = ok ? sf[cf][rr] : -1e30f;
      }
    }
    float scl_[4];
#pragma unroll
    for (int rr = 0; rr < 4; ++rr) {
      float mx = fmaxf(sv[0][rr], sv[1][rr]);
      mx = fmaxf(mx, __shfl_xor(mx, 1));
      mx = fmaxf(mx, __shfl_xor(mx, 2));
      mx = fmaxf(mx, __shfl_xor(mx, 4));
      mx = fmaxf(mx, __shfl_xor(mx, 8));
      const float mn = fmaxf(mrow[rr], mx);
      scl_[rr] = __expf(mrow[rr] - mn);
      mrow[rr] = mn;
    }
    float ps[2][4], rs[4] = {0.f, 0.f, 0.f, 0.f};
#pragma unroll
    for (int cf = 0; cf < 2; ++cf)
#pragma unroll
      for (int rr = 0; rr < 4; ++rr) {
        const float p = (sv[cf][rr] > -1e29f) ? __expf(sv[cf][rr] - mrow[rr]) : 0.f;
        ps[cf][rr] = p;
        rs[rr] += p;
      }
#pragma unroll
    for (int rr = 0; rr < 4; ++rr) {
      float r = rs[rr];
      r += __shfl_xor(r, 1);
      r += __shfl_xor(r, 2);
      r += __shfl_xor(r, 4);
      r += __shfl_xor(r, 8);
      lrow[rr] = lrow[rr] * scl_[rr] + r;
      o[0][rr] *= scl_[rr]; o[1][rr] *= scl_[rr];
      o[2][rr] *= scl_[rr]; o[3][rr] *= scl_[rr];
    }
    // ---- P -> LDS (split, swizzled [16 q][32 k]) ----
#pragma unroll
    for (int cf = 0; cf < 2; ++cf)
#pragma unroll
      for (int rr = 0; rr < 4; ++rr) {
        const int q = fg * 4 + rr, k = cf * 16 + fr;
        const int idx = q * 32 + (((k >> 3) ^ ((q >> 1) & 3)) * 8) + (k & 7);
        const unsigned short hb = f2bf(ps[cf][rr]);
        Ph[wid][idx] = hb;
        Pl[wid][idx] = f2bf(ps[cf][rr] - bf2f(hb));
      }
    const int pro = sw32(fr, fg);
    const bf16x8 pah = *(const bf16x8*)&Ph[wid][pro];
    const bf16x8 pal = *(const bf16x8*)&Pl[wid][pro];
    // ---- PV (3-term split); V rows 64B -> sw32 ----
#pragma unroll
    for (int df = 0; df < 4; ++df) {
      const int vo = sw32(df * 16 + fr, fg);
      const bf16x8 vh = *(const bf16x8*)&VH[vo];
      const bf16x8 vl = *(const bf16x8*)&VL[vo];
      o[df] = MFMA16(pal, vh, o[df]);
      o[df] = MFMA16(pah, vl, o[df]);
      o[df] = MFMA16(pah, vh, o[df]);
    }
    WAIT_VM0();
    __syncthreads();
    cur ^= 1;
  }
#undef ATTN_STAGE
  // ---- epilogue: normalize, split, store ----
#pragma unroll
  for (int df = 0; df < 4; ++df)
#pragma unroll
    for (int rr = 0; rr < 4; ++rr) {
      const int q = q0 + wid * 16 + fg * 4 + rr;
      const float v = o[df][rr] / lrow[rr];
      const long oi = ((long)(b * 2048 + q)) * 1024 + h * 64 + df * 16 + fr;
      const unsigned short hb = f2bf(v);
      Ohi[oi] = hb;
      Olo[oi] = f2bf(v - bf2f(hb));
    }
}

// ---------------------------------------------------------------------------
// Fused epilogue: residual init (out = xattn), RMSNorm2 -> H2 bf16,
// router logits (f32) -> d_out tail, top-2 + compaction lists.
// ---------------------------------------------------------------------------
__global__ __launch_bounds__(256) void router_fused_kernel(const float* __restrict__ xattn,
                                                           const float* __restrict__ scale,
                                                           const float* __restrict__ wr,
                                                           float* __restrict__ logits,
                                                           unsigned short* __restrict__ h2,
                                                           float* __restrict__ outres,
                                                           int* __restrict__ tok,
                                                           float* __restrict__ wgt,
                                                           int* __restrict__ cnt) {
  const int t = blockIdx.x, tid = threadIdx.x;
  const float4 v = *(const float4*)&xattn[(long)t * 1024 + tid * 4];
  *(float4*)&outres[(long)t * 1024 + tid * 4] = v;  // residual init of decoder_output
  float ss = v.x * v.x + v.y * v.y + v.z * v.z + v.w * v.w;
#pragma unroll
  for (int off = 32; off >= 1; off >>= 1) ss += __shfl_down(ss, off);
  __shared__ float red[4];
  __shared__ float redE[4][8];
  __shared__ float lg[8];
  if ((tid & 63) == 0) red[tid >> 6] = ss;
  __syncthreads();
  const float r = rsqrtf((red[0] + red[1] + red[2] + red[3]) * (1.0f / 1024.0f) + 1e-5f);
  const float4 sc = *(const float4*)&scale[tid * 4];
  const float hv[4] = {v.x * r * sc.x, v.y * r * sc.y, v.z * r * sc.z, v.w * r * sc.w};
  // H2 row (bit-identical to the old rmsnorm_kernel hi-path)
  ushort4 hh;
  unsigned short* hp = (unsigned short*)&hh;
#pragma unroll
  for (int i = 0; i < 4; ++i) hp[i] = f2bf(hv[i]);
  *(ushort4*)&h2[(long)t * 1024 + tid * 4] = hh;
  // router logits
  float part[8];
#pragma unroll
  for (int e = 0; e < 8; ++e) part[e] = 0.f;
#pragma unroll
  for (int i = 0; i < 4; ++i) {
    const float* w = &wr[(long)(tid * 4 + i) * 8];
#pragma unroll
    for (int e = 0; e < 8; ++e) part[e] = fmaf(hv[i], w[e], part[e]);
  }
#pragma unroll
  for (int off = 32; off >= 1; off >>= 1)
#pragma unroll
    for (int e = 0; e < 8; ++e) part[e] += __shfl_down(part[e], off);
  if ((tid & 63) == 0)
#pragma unroll
    for (int e = 0; e < 8; ++e) redE[tid >> 6][e] = part[e];
  __syncthreads();
  if (tid < 8) {
    const float l8 = redE[0][tid] + redE[1][tid] + redE[2][tid] + redE[3][tid];
    lg[tid] = l8;
    logits[(long)t * 8 + tid] = l8;
  }
  __syncthreads();
  if (tid == 0) {
    float mx = lg[0];
#pragma unroll
    for (int e = 1; e < 8; ++e) mx = fmaxf(mx, lg[e]);
    float p[8];
#pragma unroll
    for (int e = 0; e < 8; ++e) p[e] = __expf(lg[e] - mx);
    int i1 = 0;
#pragma unroll
    for (int e = 1; e < 8; ++e) if (p[e] > p[i1]) i1 = e;
    int i2 = (i1 == 0) ? 1 : 0;
#pragma unroll
    for (int e = 0; e < 8; ++e) if (e != i2 && e != i1 && p[e] > p[i2]) i2 = e;
    const float wsum = p[i1] + p[i2];
    const float w1 = p[i1] / wsum, w2 = p[i2] / wsum;
    const int pos1 = atomicAdd(&cnt[i1], 1);
    tok[i1 * 4096 + pos1] = t; wgt[i1 * 4096 + pos1] = w1;
    const int pos2 = atomicAdd(&cnt[i2], 1);
    tok[i2 * 4096 + pos2] = t; wgt[i2 * 4096 + pos2] = w2;
  }
}

// ---------------------------------------------------------------------------
// MoE gate+up fused GEMM (gathered A): act = silu(h2@Wg^T) * (h2@Wu^T), bf16
// R3 structure: 512 threads (8 waves, 2Mx4N), 3-stage pipeline, vmcnt(3).
// + XCD chunk swizzle.
// ---------------------------------------------------------------------------
__global__ __launch_bounds__(512, 4) void gateup_kernel(const unsigned short* __restrict__ H2,
                                                        const unsigned short* __restrict__ WG,
                                                        const unsigned short* __restrict__ WU,
                                                        const int* __restrict__ tok,
                                                        const int* __restrict__ cnt,
                                                        unsigned short* __restrict__ act) {
  // XCD chunk swizzle (bijective: 7168 % 8 == 0)
  const int flat = blockIdx.x + 28 * (blockIdx.y + 32 * blockIdx.z);
  const int w = (flat & 7) * 896 + (flat >> 3);
  const int bx = w % 28, by = (w / 28) & 31, e = w / 896;
  const int cn = cnt[e];
  const int m0 = by * 128;
  if (m0 >= cn) return;
  int padoff = 0;
  for (int i = 0; i < e; ++i) padoff += (cnt[i] + 127) & ~127;
  const int n0 = bx * 128;
  __shared__ unsigned short As[3][4096], Bg[3][4096], Bu[3][4096];
  const int tid = threadIdx.x, wid = tid >> 6, lane = tid & 63;
  const int wm = (wid >> 2) * 64, wn = (wid & 3) * 32;
  const int fr = lane & 15, fg = lane >> 4;
  const int srow = tid >> 2;                               // 0..127
  const int scol = (((tid & 3) ^ ((tid >> 3) & 3))) * 8;   // swizzled source chunk
  const int lr = m0 + srow;
  const int tkr = (lr < cn) ? tok[e * 4096 + lr] : 0;
  const unsigned short* ga = H2 + (long)tkr * 1024 + scol;
  const unsigned short* gb = WG + (long)e * 3584 * 1024 + (long)(n0 + srow) * 1024 + scol;
  const unsigned short* gu = WU + (long)e * 3584 * 1024 + (long)(n0 + srow) * 1024 + scol;
#define GU_STAGE(s, b)                                                         \
  do {                                                                         \
    const int ko = (s) * 32;                                                   \
    GL16(ga + ko, (char*)As[b] + wid * 1024);                                  \
    GL16(gb + ko, (char*)Bg[b] + wid * 1024);                                  \
    GL16(gu + ko, (char*)Bu[b] + wid * 1024);                                  \
  } while (0)
  f32x4 ag[4][2] = {}, au[4][2] = {};
  GU_STAGE(0, 0);
  GU_STAGE(1, 1);
  PIPE_SYNC(3);
  for (int t = 0; t < 32; ++t) {
    const int cb = t % 3;
    if (t + 2 < 32) GU_STAGE(t + 2, (t + 2) % 3);
    const unsigned short* As_ = As[cb];
    const unsigned short* Bg_ = Bg[cb];
    const unsigned short* Bu_ = Bu[cb];
    bf16x8 af[4], bgf[2], buf_[2];
#pragma unroll
    for (int i = 0; i < 4; ++i) af[i] = *(const bf16x8*)&As_[sw32(wm + i * 16 + fr, fg)];
#pragma unroll
    for (int j = 0; j < 2; ++j) {
      const int oB = sw32(wn + j * 16 + fr, fg);
      bgf[j] = *(const bf16x8*)&Bg_[oB];
      buf_[j] = *(const bf16x8*)&Bu_[oB];
    }
    SETPRIO(1);
#pragma unroll
    for (int i = 0; i < 4; ++i)
#pragma unroll
      for (int j = 0; j < 2; ++j) {
        ag[i][j] = MFMA16(af[i], bgf[j], ag[i][j]);
        au[i][j] = MFMA16(af[i], buf_[j], au[i][j]);
      }
    SETPRIO(0);
    if (t + 2 < 32) PIPE_SYNC(3);
    else if (t + 1 < 32) PIPE_SYNC(0);
  }
#undef GU_STAGE
  const int cr = fg * 4;
#pragma unroll
  for (int i = 0; i < 4; ++i)
#pragma unroll
    for (int j = 0; j < 2; ++j)
#pragma unroll
      for (int rr = 0; rr < 4; ++rr) {
        const int row = wm + i * 16 + cr + rr;  // tile-local
        const int col = n0 + wn + j * 16 + fr;
        const float gv = ag[i][j][rr];
        const float sg = gv / (1.f + __expf(-gv));  // silu
        act[(long)(padoff + m0 + row) * 3584 + col] = f2bf(sg * au[i][j][rr]);
      }
}

// MoE down GEMM + scatter: out[tok] += w * (act @ Wd^T)
// R6-exact: 512 threads (8 waves, 2Mx4N), wave 64x32, 3-stage vmcnt(2),
// XCD chunk swizzle (nwg=2048, 256/XCD = 1 expert). Twice-verified best.
__global__ __launch_bounds__(512, 4) void down_kernel(const unsigned short* __restrict__ act,
                                                      const unsigned short* __restrict__ WD,
                                                      const int* __restrict__ tok,
                                                      const float* __restrict__ wgt,
                                                      const int* __restrict__ cnt,
                                                      float* __restrict__ out) {
  const int flat = blockIdx.x + 8 * (blockIdx.y + 32 * blockIdx.z);
  const int w = (flat & 7) * 256 + (flat >> 3);
  const int bx = w & 7, by = (w >> 3) & 31, e = w >> 8;
  const int cn = cnt[e];
  const int m0 = by * 128;
  if (m0 >= cn) return;
  int padoff = 0;
  for (int i = 0; i < e; ++i) padoff += (cnt[i] + 127) & ~127;
  const int n0 = bx * 128;
  __shared__ unsigned short As[3][4096], Bs[3][4096];
  const int tid = threadIdx.x, wid = tid >> 6, lane = tid & 63;
  const int wm = (wid >> 2) * 64, wn = (wid & 3) * 32;
  const int fr = lane & 15, fg = lane >> 4;
  const int srow = tid >> 2;                               // 0..127
  const int scol = (((tid & 3) ^ ((tid >> 3) & 3))) * 8;   // swizzled source chunk
  const unsigned short* ga = act + (long)(padoff + m0 + srow) * 3584 + scol;
  const unsigned short* gb = WD + (long)e * 1024 * 3584 + (long)(n0 + srow) * 3584 + scol;
#define DN_STAGE(s, b)                                                         \
  do {                                                                         \
    const int ko = (s) * 32;                                                   \
    GL16(ga + ko, (char*)As[b] + wid * 1024);                                  \
    GL16(gb + ko, (char*)Bs[b] + wid * 1024);                                  \
  } while (0)
  f32x4 acc[4][2] = {};
  DN_STAGE(0, 0);
  DN_STAGE(1, 1);
  PIPE_SYNC(2);
  for (int t = 0; t < 112; ++t) {
    const int cb = t % 3;
    if (t + 2 < 112) DN_STAGE(t + 2, (t + 2) % 3);
    const unsigned short* As_ = As[cb];
    const unsigned short* Bs_ = Bs[cb];
    bf16x8 af[4], bf_[2];
#pragma unroll
    for (int i = 0; i < 4; ++i) af[i] = *(const bf16x8*)&As_[sw32(wm + i * 16 + fr, fg)];
#pragma unroll
    for (int j = 0; j < 2; ++j) bf_[j] = *(const bf16x8*)&Bs_[sw32(wn + j * 16 + fr, fg)];
    SETPRIO(1);
#pragma unroll
    for (int i = 0; i < 4; ++i)
#pragma unroll
      for (int j = 0; j < 2; ++j)
        acc[i][j] = MFMA16(af[i], bf_[j], acc[i][j]);
    SETPRIO(0);
    if (t + 2 < 112) PIPE_SYNC(2);
    else if (t + 1 < 112) PIPE_SYNC(0);
  }
#undef DN_STAGE
  const int cr = fg * 4;
#pragma unroll
  for (int i = 0; i < 4; ++i)
#pragma unroll
    for (int rr = 0; rr < 4; ++rr) {
      const int lrow = m0 + wm + i * 16 + cr + rr;
      if (lrow < cn) {
        const int tk = tok[e * 4096 + lrow];
        const float wv_ = wgt[e * 4096 + lrow];
#pragma unroll
        for (int j = 0; j < 2; ++j)
          atomicAdd(&out[(long)tk * 1024 + n0 + wn + j * 16 + fr], wv_ * acc[i][j][rr]);
      }
    }
}

// ---------------------------------------------------------------------------
extern "C" void kernel_launch(void* const* d_in, const int* in_sizes, int n_in,
                              void* d_out, int out_size, void* d_ws, size_t ws_size,
                              hipStream_t stream) {
  (void)in_sizes; (void)n_in; (void)out_size;
  if (ws_size < WS_NEED) {
    fprintf(stderr, "kernel_launch: ws too small: %zu < %zu\n", ws_size, (size_t)WS_NEED);
  }
  const float* x    = (const float*)d_in[0];
  const float* n1s  = (const float*)d_in[1];
  const float* n2s  = (const float*)d_in[2];
  const float* wq   = (const float*)d_in[3];
  const float* wk   = (const float*)d_in[4];
  const float* wv   = (const float*)d_in[5];
  const float* wo   = (const float*)d_in[6];
  const float* wrt  = (const float*)d_in[7];
  const float* wg   = (const float*)d_in[8];
  const float* wu   = (const float*)d_in[9];
  const float* wd   = (const float*)d_in[10];
  float* out = (float*)d_out;
  char* W = (char*)d_ws;

  unsigned short* WQH = (unsigned short*)(W + O_WQKVT_HI);
  unsigned short* WQL = (unsigned short*)(W + O_WQKVT_LO);
  unsigned short* WOH = (unsigned short*)(W + O_WOT_HI);
  unsigned short* WOL = (unsigned short*)(W + O_WOT_LO);
  unsigned short* WGT = (unsigned short*)(W + O_WGT);
  unsigned short* WUT = (unsigned short*)(W + O_WUT);
  unsigned short* WDT = (unsigned short*)(W + O_WDT);
  unsigned short* H2  = (unsigned short*)(W + O_H2);
  int* TOK    = (int*)(W + O_TOK);
  float* WGTL = (float*)(W + O_WGTL);
  int* CNT    = (int*)(W + O_CNT);
  unsigned short* HSH = (unsigned short*)(W + O_HSHI);
  unsigned short* HSL = (unsigned short*)(W + O_HSLO);
  float* QKV = (float*)(W + O_QKV);
  unsigned short* QHI = (unsigned short*)(W + O_QHI);
  unsigned short* QLO = (unsigned short*)(W + O_QLO);
  unsigned short* KHI = (unsigned short*)(W + O_KHI);
  unsigned short* KLO = (unsigned short*)(W + O_KLO);
  unsigned short* VTH = (unsigned short*)(W + O_VTH);
  unsigned short* VTL = (unsigned short*)(W + O_VTL);
  unsigned short* AHI = (unsigned short*)(W + O_AHI);
  unsigned short* ALO = (unsigned short*)(W + O_ALO);
  float* XATTN = (float*)(W + O_XATTN);
  unsigned short* ACT = (unsigned short*)(W + O_ACT);
  float2* ROPET = (float2*)(W + O_ROPET);  // aliases AHI (dead until attn)

  // RoPE table + cnt zeroing (table region overwritten later by attn's AHI)
  rope_table_kernel<<<256, 256, 0, stream>>>(ROPET, CNT);
  // RMSNorm1 -> split hs
  rmsnorm_kernel<<<4096, 256, 0, stream>>>(x, n1s, HSH, HSL);
  // weight transposes (merged small 4; big expert mats as before)
  transpose_cvt_split4<<<dim3(16, 16, 4), 256, 0, stream>>>(wq, wk, wv, wo,
                                                            WQH, WQL, WOH, WOL);
  transpose_cvt<<<dim3(56, 16, 8), 256, 0, stream>>>(wg, WGT, 1024, 3584, 1024L * 3584, 3584L * 1024);
  transpose_cvt<<<dim3(56, 16, 8), 256, 0, stream>>>(wu, WUT, 1024, 3584, 1024L * 3584, 3584L * 1024);
  transpose_cvt<<<dim3(16, 56, 8), 256, 0, stream>>>(wd, WDT, 3584, 1024, 3584L * 1024, 1024L * 3584);
  // QKV projection (split GEMM, f32 out)
  gemm_split<<<dim3(12, 32, 1), 256, 0, stream>>>(HSH, HSL, WQH, WQL, nullptr, QKV, 4096, 1536, 1024);
  // RoPE + split (table-driven); V transpose + split
  rope_kernel<<<4096, 256, 0, stream>>>(QKV, ROPET, QHI, QLO, KHI, KLO);
  vt_split_kernel<<<dim3(32, 4, 2), 256, 0, stream>>>(QKV, VTH, VTL);
  // attention (overwrites the table region with AHI — table already consumed)
  attn_kernel<<<dim3(32, 16, 2), 256, 0, stream>>>(QHI, QLO, KHI, KLO, VTH, VTL, AHI, ALO);
  // out projection + residual
  gemm_split<<<dim3(8, 32, 1), 256, 0, stream>>>(AHI, ALO, WOH, WOL, x, XATTN, 4096, 1024, 1024);
  // fused: residual init + RMSNorm2 -> H2 + router -> logits/lists
  router_fused_kernel<<<4096, 256, 0, stream>>>(XATTN, n2s, wrt, out + 4194304, H2, out,
                                                TOK, WGTL, CNT);
  gateup_kernel<<<dim3(28, 32, 8), 512, 0, stream>>>(H2, WGT, WUT, TOK, CNT, ACT);
  down_kernel<<<dim3(8, 32, 8), 512, 0, stream>>>(ACT, WDT, TOK, WGTL, CNT, out);
}